// Round 4
// baseline (191.157 us; speedup 1.0000x reference)
//
#include <hip/hip_runtime.h>
#include <math.h>

#define NA 2048
#define CD 128
#define NC ((size_t)262144)   // NA*CD

typedef unsigned short u16;
typedef short s8v __attribute__((ext_vector_type(8)));
typedef float f4v __attribute__((ext_vector_type(4)));
#define MFMA __builtin_amdgcn_mfma_f32_16x16x32_bf16

__device__ __forceinline__ float sigm(float x) { return 1.f / (1.f + __expf(-x)); }
__device__ __forceinline__ u16 f2bf(float x) {
    unsigned u = __float_as_uint(x);
    u += 0x7fffu + ((u >> 16) & 1u);
    return (u16)(u >> 16);
}
__device__ __forceinline__ float bf2f(u16 h) { return __uint_as_float((unsigned)h << 16); }

// ---------------- weight prep: transpose + gamma-fold + bf16 hi/lo split ----------------
// BP1 [3][768][128]  rows: 0-127 g_a*wsigA^T | 128-255 g_a*wskipA^T | 256-383 g_t*wsigT^T
//                          | 384-511 g_t*wskipT^T | 512-639 w_ao^T | 640-767 w_to^T
// BG1 [3][1024][128] rows: wq^T | wk^T | wv^T | w_gate^T | w_t1^T(256) | w_t2^T(256)
// BG2 [3][128][384]  [c][k]: k<128 w_out[k][c] else w_t3[k-128][c]
__global__ __launch_bounds__(256)
void prep_w(const float* __restrict__ attn_gamma, const float* __restrict__ attn_wsig,
            const float* __restrict__ attn_bsig, const float* __restrict__ attn_wskip,
            const float* __restrict__ wq, const float* __restrict__ wk,
            const float* __restrict__ wv, const float* __restrict__ w_gate,
            const float* __restrict__ w_out, const float* __restrict__ w_ao,
            const float* __restrict__ b_ao,
            const float* __restrict__ tr_gamma, const float* __restrict__ tr_wsig,
            const float* __restrict__ tr_bsig, const float* __restrict__ tr_wskip,
            const float* __restrict__ w_t1, const float* __restrict__ w_t2,
            const float* __restrict__ w_t3, const float* __restrict__ w_to,
            const float* __restrict__ b_to,
            u16* __restrict__ BP1h, u16* __restrict__ BP1l,
            u16* __restrict__ BG1h, u16* __restrict__ BG1l,
            u16* __restrict__ BG2h, u16* __restrict__ BG2l,
            float* __restrict__ Pbias) {
    int e = blockIdx.x * 256 + threadIdx.x;
    if (e >= 835584) {
        int t = e - 835584;
        if (t < 2304) {
            int z = t / 768, rem = t % 768, j = rem >> 7, c = rem & 127;
            float v = 0.f;
            if (j == 0) v = attn_bsig[z * 128 + c];
            else if (j == 2) v = tr_bsig[z * 128 + c];
            else if (j == 4) v = b_ao[z * 128 + c];
            else if (j == 5) v = b_to[z * 128 + c];
            Pbias[t] = v;
        }
        return;
    }
    int z = e / 278528, r = e % 278528;
    float val;
    u16 *dh, *dl;
    size_t dofs;
    if (r < 98304) {
        int c = r >> 7, k = r & 127, seg = c >> 7, cc = c & 127;
        const float* w;
        const float* g = nullptr;
        switch (seg) {
            case 0: w = attn_wsig; g = attn_gamma; break;
            case 1: w = attn_wskip; g = attn_gamma; break;
            case 2: w = tr_wsig; g = tr_gamma; break;
            case 3: w = tr_wskip; g = tr_gamma; break;
            case 4: w = w_ao; break;
            default: w = w_to; break;
        }
        val = w[((size_t)z * 128 + k) * 128 + cc];
        if (g) val *= g[z * 128 + k];
        dh = BP1h; dl = BP1l; dofs = (size_t)z * 98304 + r;
    } else if (r < 229376) {
        int t = r - 98304, c = t >> 7, k = t & 127;
        if (c < 512) {
            int seg = c >> 7, cc = c & 127;
            const float* w = (seg == 0) ? wq : (seg == 1) ? wk : (seg == 2) ? wv : w_gate;
            val = w[((size_t)z * 128 + k) * 128 + cc];
        } else {
            int tt = c - 512;
            const float* w = (tt < 256) ? w_t1 : w_t2;
            val = w[(size_t)z * 32768 + (size_t)k * 256 + (tt & 255)];
        }
        dh = BG1h; dl = BG1l; dofs = (size_t)z * 131072 + t;
    } else {
        int t = r - 229376, c = t / 384, k = t % 384;
        val = (k < 128) ? w_out[((size_t)z * 128 + k) * 128 + c]
                        : w_t3[(size_t)z * 32768 + (size_t)(k - 128) * 128 + c];
        dh = BG2h; dl = BG2l; dofs = (size_t)z * 49152 + t;
    }
    u16 h = f2bf(val);
    dh[dofs] = h;
    dl[dofs] = f2bf(val - bf2f(h));
}

// ---------------- pb: LN(plm slice)*lnz_g+lnz_b @ w_pair, all 3 blocks ----------------
// pb layout: [3][64 qblk][4 h][32 q][128 kl] ; kl >= nk entries are zero-filled
__global__ __launch_bounds__(256)
void pb_kernel(const float* __restrict__ plm, const float* __restrict__ lnz_g,
               const float* __restrict__ lnz_b, const float* __restrict__ w_pair,
               float* __restrict__ pb) {
    __shared__ float gw[3][4][16];
    __shared__ float c0s[3][4];
    int t = threadIdx.x;
    if (t < 12) {
        int i = t >> 2, h = t & 3;
        float c = 0.f;
        for (int cp = 0; cp < 16; ++cp) {
            float wp = w_pair[(i * 16 + cp) * 4 + h];
            gw[i][h][cp] = lnz_g[i * 16 + cp] * wp;
            c += lnz_b[i * 16 + cp] * wp;
        }
        c0s[i][h] = c;
    }
    __syncthreads();
    int c = blockIdx.x;
    int p = blockIdx.y * 256 + t;
    int ql = p >> 7, kl = p & 127;
    int kstart = max(0, c * 32 - 48), kend = min(2048, c * 32 + 80);
    int k = kstart + kl;
    if (k >= kend) {
        // fully initialize the buffer (never read, but keep ws state call-invariant)
#pragma unroll
        for (int i = 0; i < 3; ++i)
#pragma unroll
            for (int h = 0; h < 4; ++h)
                pb[((((size_t)i * 64 + c) * 4 + h) * 32 + ql) * 128 + kl] = 0.f;
        return;
    }
    int q = c * 32 + ql;
    const float* row = plm + ((size_t)q * 2048 + (size_t)k) * 16;
    float x[16];
#pragma unroll
    for (int j = 0; j < 4; ++j) {
        float4 v = *(const float4*)(row + j * 4);
        x[j * 4 + 0] = v.x; x[j * 4 + 1] = v.y; x[j * 4 + 2] = v.z; x[j * 4 + 3] = v.w;
    }
    float s = 0.f, sq = 0.f;
#pragma unroll
    for (int cp = 0; cp < 16; ++cp) { s += x[cp]; sq += x[cp] * x[cp]; }
    float mean = s * (1.f / 16.f);
    float var = sq * (1.f / 16.f) - mean * mean;
    float r = 1.f / sqrtf(var + 1e-5f);
    float xn[16];
#pragma unroll
    for (int cp = 0; cp < 16; ++cp) xn[cp] = (x[cp] - mean) * r;
#pragma unroll
    for (int i = 0; i < 3; ++i)
#pragma unroll
        for (int h = 0; h < 4; ++h) {
            float d = c0s[i][h];
#pragma unroll
            for (int cp = 0; cp < 16; ++cp) d = fmaf(xn[cp], gw[i][h][cp], d);
            pb[((((size_t)i * 64 + c) * 4 + h) * 32 + ql) * 128 + kl] = d;
        }
}

// ---------------- P1 fused: LN(cl) in-block -> sg streams for all 3 z ----------------
__global__ __launch_bounds__(256)
void mf_p1f(const float* __restrict__ cl, const u16* __restrict__ B1h, const u16* __restrict__ B1l,
            const float* __restrict__ Pbias, float* __restrict__ sg) {
    const int r0 = blockIdx.x * 32, chunk = blockIdx.y, z = blockIdx.z;
    __shared__ u16 Ah[32 * 128], Al[32 * 128];
    {
        const int tid = threadIdx.x;
        const int row = tid >> 3, cb = (tid & 7) * 16;
        const float* ar = cl + (size_t)(r0 + row) * CD + cb;
        float x[16];
#pragma unroll
        for (int j = 0; j < 4; ++j) {
            float4 v = *(const float4*)(ar + j * 4);
            x[4 * j] = v.x; x[4 * j + 1] = v.y; x[4 * j + 2] = v.z; x[4 * j + 3] = v.w;
        }
        float s = 0.f, sq = 0.f;
#pragma unroll
        for (int j = 0; j < 16; ++j) { s += x[j]; sq += x[j] * x[j]; }
#pragma unroll
        for (int m = 1; m < 8; m <<= 1) { s += __shfl_xor(s, m); sq += __shfl_xor(sq, m); }
        float mean = s * (1.f / 128.f), var = sq * (1.f / 128.f) - mean * mean;
        float rr = 1.f / sqrtf(var + 1e-5f);
#pragma unroll
        for (int gp = 0; gp < 2; ++gp) {
            u16 hv8[8], lv8[8];
#pragma unroll
            for (int j = 0; j < 8; ++j) {
                float xv = x[gp * 8 + j];
                float val = (chunk < 4) ? (xv - mean) * rr : xv;
                u16 hh = f2bf(val);
                hv8[j] = hh; lv8[j] = f2bf(val - bf2f(hh));
            }
            int g = ((cb >> 3) + gp) ^ (row & 7);
            *(s8v*)(Ah + row * 128 + g * 8) = *(s8v*)hv8;
            *(s8v*)(Al + row * 128 + g * 8) = *(s8v*)lv8;
        }
    }
    __syncthreads();
    const int l = threadIdx.x & 63, w = threadIdx.x >> 6;
    const int lr = l & 15, lq = l >> 4, kg = lq * 8;
    const int c0 = w * 32;
    const u16* Bh = B1h + (size_t)z * 98304 + (size_t)chunk * 16384;
    const u16* Bl = B1l + (size_t)z * 98304 + (size_t)chunk * 16384;
    f4v acc[2][2] = {};
#pragma unroll
    for (int ks = 0; ks < 4; ++ks) {
        int g = (4 * ks + lq) ^ (lr & 7);
        s8v a0h = *(const s8v*)(Ah + lr * 128 + g * 8);
        s8v a1h = *(const s8v*)(Ah + (16 + lr) * 128 + g * 8);
        s8v a0l = *(const s8v*)(Al + lr * 128 + g * 8);
        s8v a1l = *(const s8v*)(Al + (16 + lr) * 128 + g * 8);
        s8v b0h = *(const s8v*)(Bh + (size_t)(c0 + lr) * 128 + ks * 32 + kg);
        s8v b1h = *(const s8v*)(Bh + (size_t)(c0 + 16 + lr) * 128 + ks * 32 + kg);
        s8v b0l = *(const s8v*)(Bl + (size_t)(c0 + lr) * 128 + ks * 32 + kg);
        s8v b1l = *(const s8v*)(Bl + (size_t)(c0 + 16 + lr) * 128 + ks * 32 + kg);
        acc[0][0] = MFMA(a0h, b0h, acc[0][0], 0, 0, 0); acc[0][1] = MFMA(a0h, b1h, acc[0][1], 0, 0, 0);
        acc[1][0] = MFMA(a1h, b0h, acc[1][0], 0, 0, 0); acc[1][1] = MFMA(a1h, b1h, acc[1][1], 0, 0, 0);
        acc[0][0] = MFMA(a0h, b0l, acc[0][0], 0, 0, 0); acc[0][1] = MFMA(a0h, b1l, acc[0][1], 0, 0, 0);
        acc[1][0] = MFMA(a1h, b0l, acc[1][0], 0, 0, 0); acc[1][1] = MFMA(a1h, b1l, acc[1][1], 0, 0, 0);
        acc[0][0] = MFMA(a0l, b0h, acc[0][0], 0, 0, 0); acc[0][1] = MFMA(a0l, b1h, acc[0][1], 0, 0, 0);
        acc[1][0] = MFMA(a1l, b0h, acc[1][0], 0, 0, 0); acc[1][1] = MFMA(a1l, b1h, acc[1][1], 0, 0, 0);
    }
    const bool dosig = (chunk != 1) && (chunk != 3);
    const float* bp = Pbias + (z * 6 + chunk) * 128;
    float* dst = sg + ((size_t)z * 6 + chunk) * NC;
#pragma unroll
    for (int mi = 0; mi < 2; ++mi)
#pragma unroll
        for (int i = 0; i < 4; ++i) {
            int row = r0 + mi * 16 + lq * 4 + i;
#pragma unroll
            for (int ni = 0; ni < 2; ++ni) {
                int col = c0 + ni * 16 + lr;
                float xx = acc[mi][ni][i];
                if (dosig) xx = sigm(xx + bp[col]);
                dst[(size_t)row * CD + col] = xx;
            }
        }
}

// ---------------- K1: fused adaLN(a) + QKVG/t1t2 GEMM ----------------
// grid (64, 4): y=0,1 -> an (chunks 0..3); y=2,3 -> tn (chunks 4..7)
__global__ __launch_bounds__(256)
void k1_fused(const float* __restrict__ a, const float* __restrict__ sgi,
              const u16* __restrict__ B1h, const u16* __restrict__ B1l,
              const float* __restrict__ bq,
              u16* __restrict__ qgh, u16* __restrict__ qgl,
              u16* __restrict__ vTh, u16* __restrict__ vTl,
              float* __restrict__ tbuf) {
    const int r0 = blockIdx.x * 32;
    const int y = blockIdx.y;
    __shared__ u16 Ah[32 * 128], Al[32 * 128];
    {
        const int tid = threadIdx.x;
        const int row = tid >> 3, cb = (tid & 7) * 16;
        const float* ar = a + (size_t)(r0 + row) * CD + cb;
        float x[16];
#pragma unroll
        for (int j = 0; j < 4; ++j) {
            float4 v = *(const float4*)(ar + j * 4);
            x[4 * j] = v.x; x[4 * j + 1] = v.y; x[4 * j + 2] = v.z; x[4 * j + 3] = v.w;
        }
        float s = 0.f, sq = 0.f;
#pragma unroll
        for (int j = 0; j < 16; ++j) { s += x[j]; sq += x[j] * x[j]; }
#pragma unroll
        for (int m = 1; m < 8; m <<= 1) { s += __shfl_xor(s, m); sq += __shfl_xor(sq, m); }
        float mean = s * (1.f / 128.f), var = sq * (1.f / 128.f) - mean * mean;
        float rr = 1.f / sqrtf(var + 1e-5f);
        const float* sig = sgi + ((y < 2) ? 0 : 2 * NC) + (size_t)(r0 + row) * CD + cb;
        const float* skp = sgi + ((y < 2) ? NC : 3 * NC) + (size_t)(r0 + row) * CD + cb;
#pragma unroll
        for (int gp = 0; gp < 2; ++gp) {
            u16 hv8[8], lv8[8];
#pragma unroll
            for (int j = 0; j < 8; ++j) {
                int jj = gp * 8 + j;
                float ln = (x[jj] - mean) * rr;
                float val = fmaf(sig[jj], ln, skp[jj]);
                u16 hh = f2bf(val);
                hv8[j] = hh; lv8[j] = f2bf(val - bf2f(hh));
            }
            int g = ((cb >> 3) + gp) ^ (row & 7);
            *(s8v*)(Ah + row * 128 + g * 8) = *(s8v*)hv8;
            *(s8v*)(Al + row * 128 + g * 8) = *(s8v*)lv8;
        }
    }
    __syncthreads();
    const int l = threadIdx.x & 63, w = threadIdx.x >> 6;
    const int lr = l & 15, lq = l >> 4, kg = lq * 8;
    const int chunk = 2 * y + (w >> 1);
    const int cbase = (w & 1) * 64;
    f4v acc[2][2][2] = {};   // [t2][mi][ni]
#pragma unroll
    for (int ks = 0; ks < 4; ++ks) {
        int g = (4 * ks + lq) ^ (lr & 7);
        s8v a0h = *(const s8v*)(Ah + lr * 128 + g * 8);
        s8v a1h = *(const s8v*)(Ah + (16 + lr) * 128 + g * 8);
        s8v a0l = *(const s8v*)(Al + lr * 128 + g * 8);
        s8v a1l = *(const s8v*)(Al + (16 + lr) * 128 + g * 8);
#pragma unroll
        for (int t2 = 0; t2 < 2; ++t2) {
            int crow = chunk * 128 + cbase + t2 * 32;
            s8v b0h = *(const s8v*)(B1h + (size_t)(crow + lr) * 128 + ks * 32 + kg);
            s8v b1h = *(const s8v*)(B1h + (size_t)(crow + 16 + lr) * 128 + ks * 32 + kg);
            s8v b0l = *(const s8v*)(B1l + (size_t)(crow + lr) * 128 + ks * 32 + kg);
            s8v b1l = *(const s8v*)(B1l + (size_t)(crow + 16 + lr) * 128 + ks * 32 + kg);
            acc[t2][0][0] = MFMA(a0h, b0h, acc[t2][0][0], 0, 0, 0);
            acc[t2][0][1] = MFMA(a0h, b1h, acc[t2][0][1], 0, 0, 0);
            acc[t2][1][0] = MFMA(a1h, b0h, acc[t2][1][0], 0, 0, 0);
            acc[t2][1][1] = MFMA(a1h, b1h, acc[t2][1][1], 0, 0, 0);
            acc[t2][0][0] = MFMA(a0h, b0l, acc[t2][0][0], 0, 0, 0);
            acc[t2][0][1] = MFMA(a0h, b1l, acc[t2][0][1], 0, 0, 0);
            acc[t2][1][0] = MFMA(a1h, b0l, acc[t2][1][0], 0, 0, 0);
            acc[t2][1][1] = MFMA(a1h, b1l, acc[t2][1][1], 0, 0, 0);
            acc[t2][0][0] = MFMA(a0l, b0h, acc[t2][0][0], 0, 0, 0);
            acc[t2][0][1] = MFMA(a0l, b1h, acc[t2][0][1], 0, 0, 0);
            acc[t2][1][0] = MFMA(a1l, b0h, acc[t2][1][0], 0, 0, 0);
            acc[t2][1][1] = MFMA(a1l, b1h, acc[t2][1][1], 0, 0, 0);
        }
    }
#pragma unroll
    for (int t2 = 0; t2 < 2; ++t2)
#pragma unroll
        for (int mi = 0; mi < 2; ++mi)
#pragma unroll
            for (int i = 0; i < 4; ++i) {
                int row = r0 + mi * 16 + lq * 4 + i;
#pragma unroll
                for (int ni = 0; ni < 2; ++ni) {
                    int gcol = chunk * 128 + cbase + t2 * 32 + ni * 16 + lr;
                    float x = acc[t2][mi][ni][i];
                    if (chunk == 0) x += bq[gcol];
                    if (gcol < 512) {
                        u16 hh = f2bf(x), ll = f2bf(x - bf2f(hh));
                        qgh[(size_t)row * 512 + gcol] = hh;
                        qgl[(size_t)row * 512 + gcol] = ll;
                        if (chunk == 2) {
                            int cv = gcol - 256;
                            vTh[(size_t)cv * 2048 + row] = hh;
                            vTl[(size_t)cv * 2048 + row] = ll;
                        }
                    } else {
                        tbuf[(size_t)row * 512 + (gcol - 512)] = x;
                    }
                }
            }
}

// ---------------- attn: MFMA QK^T + in-register softmax + MFMA PV ----------------
// grid (64, 4), 64 threads (1 wave) per block; block = (qblock c, head h)
__global__ __launch_bounds__(64)
void attn_mfma(const u16* __restrict__ qgh, const u16* __restrict__ qgl,
               const u16* __restrict__ vTh, const u16* __restrict__ vTl,
               const float* __restrict__ pb, const float* __restrict__ atom_mask,
               u16* __restrict__ ogh, u16* __restrict__ ogl) {
    const int c = blockIdx.x, h = blockIdx.y;
    const int l = threadIdx.x;
    const int kstart = max(0, c * 32 - 48);
    const int kend = min(2048, c * 32 + 80);
    const int nk = kend - kstart;
    const int lr = l & 15, lq = l >> 4, kg = lq * 8;

    __shared__ u16 Pls[32 * 128];

    // Q fragments (hi/lo), rows c*32 + mi*16 + lr, k = d
    s8v qfh[2], qfl[2];
#pragma unroll
    for (int mi = 0; mi < 2; ++mi) {
        size_t qb = (size_t)(c * 32 + mi * 16 + lr) * 512 + h * 32 + kg;
        qfh[mi] = *(const s8v*)(qgh + qb);
        qfl[mi] = *(const s8v*)(qgl + qb);
    }
    // QK^T: 2 q-tiles x 8 k-tiles, 3-term
    f4v lac[2][8] = {};
#pragma unroll
    for (int kt = 0; kt < 8; ++kt) {
        int krow = min(kstart + kt * 16 + lr, 2047);
        size_t kb = (size_t)krow * 512 + 128 + h * 32 + kg;
        s8v bh = *(const s8v*)(qgh + kb);
        s8v bl = *(const s8v*)(qgl + kb);
        lac[0][kt] = MFMA(qfh[0], bh, lac[0][kt], 0, 0, 0);
        lac[1][kt] = MFMA(qfh[1], bh, lac[1][kt], 0, 0, 0);
        lac[0][kt] = MFMA(qfh[0], bl, lac[0][kt], 0, 0, 0);
        lac[1][kt] = MFMA(qfh[1], bl, lac[1][kt], 0, 0, 0);
        lac[0][kt] = MFMA(qfl[0], bh, lac[0][kt], 0, 0, 0);
        lac[1][kt] = MFMA(qfl[1], bh, lac[1][kt], 0, 0, 0);
    }
    // mask bias per kt (kl = kt*16 + lr)
    float mb8[8];
#pragma unroll
    for (int kt = 0; kt < 8; ++kt) {
        int kl = kt * 16 + lr;
        mb8[kt] = (kl < nk) ? (atom_mask[kstart + kl] - 1.f) * 1.0e9f : 0.f;
    }
    const float scale = 0.17677669529663687f;
    const float* pbp = pb + (size_t)((c * 4 + h) * 32) * 128;
    float inv_s[2][4];
#pragma unroll
    for (int mi = 0; mi < 2; ++mi)
#pragma unroll
        for (int i = 0; i < 4; ++i) {
            const int rl = mi * 16 + lq * 4 + i;
            float lg[8];
#pragma unroll
            for (int kt = 0; kt < 8; ++kt) {
                int kl = kt * 16 + lr;
                float v = -1e30f;
                if (kl < nk) v = fmaf(lac[mi][kt][i], scale, pbp[(size_t)rl * 128 + kl] + mb8[kt]);
                lg[kt] = v;
            }
            float m = lg[0];
#pragma unroll
            for (int kt = 1; kt < 8; ++kt) m = fmaxf(m, lg[kt]);
#pragma unroll
            for (int msk = 1; msk < 16; msk <<= 1) m = fmaxf(m, __shfl_xor(m, msk));
            float ssum = 0.f;
#pragma unroll
            for (int kt = 0; kt < 8; ++kt) {
                float p = __expf(lg[kt] - m);
                u16 p16 = f2bf(p);
                ssum += bf2f(p16);
                int kl = kt * 16 + lr;
                int g = (kl >> 3) ^ (rl & 7);
                Pls[rl * 128 + g * 8 + (kl & 7)] = p16;
            }
#pragma unroll
            for (int msk = 1; msk < 16; msk <<= 1) ssum += __shfl_xor(ssum, msk);
            inv_s[mi][i] = 1.f / ssum;
        }
    __syncthreads();   // LDS ordering fence: P fully stored before vector re-read
    // PV: A = P (bf16 hi only, from LDS), B = V^T hi/lo
    f4v oac[2][2] = {};
#pragma unroll
    for (int ks = 0; ks < 4; ++ks) {
        s8v pA[2];
#pragma unroll
        for (int mi = 0; mi < 2; ++mi) {
            int row = mi * 16 + lr;
            int g = (4 * ks + lq) ^ (row & 7);
            pA[mi] = *(const s8v*)(Pls + row * 128 + g * 8);
        }
#pragma unroll
        for (int ct = 0; ct < 2; ++ct) {
            size_t vb = (size_t)(h * 32 + ct * 16 + lr) * 2048 + kstart + ks * 32 + kg;
            s8v vh = *(const s8v*)(vTh + vb);
            s8v vl = *(const s8v*)(vTl + vb);
            oac[0][ct] = MFMA(pA[0], vh, oac[0][ct], 0, 0, 0);
            oac[1][ct] = MFMA(pA[1], vh, oac[1][ct], 0, 0, 0);
            oac[0][ct] = MFMA(pA[0], vl, oac[0][ct], 0, 0, 0);
            oac[1][ct] = MFMA(pA[1], vl, oac[1][ct], 0, 0, 0);
        }
    }
    // epilogue: normalize, gate, split, store og
#pragma unroll
    for (int mi = 0; mi < 2; ++mi)
#pragma unroll
        for (int ct = 0; ct < 2; ++ct)
#pragma unroll
            for (int i = 0; i < 4; ++i) {
                int rl = mi * 16 + lq * 4 + i;
                int row = c * 32 + rl;
                int d = ct * 16 + lr;
                float o = oac[mi][ct][i] * inv_s[mi][i];
                size_t gidx = (size_t)row * 512 + 384 + h * 32 + d;
                float g = bf2f(qgh[gidx]) + bf2f(qgl[gidx]);
                float v = o * sigm(g);
                u16 hh = f2bf(v);
                size_t oi = (size_t)row * 128 + h * 32 + d;
                ogh[oi] = hh;
                ogl[oi] = f2bf(v - bf2f(hh));
            }
}

// ---------------- K3: fused swiglu + final dual GEMM ----------------
// grid 64, 256 thr. dst = sg4*(og@w_out) + sg5*(silu(t1)*t2 @ w_t3)
__global__ __launch_bounds__(256)
void k3_fused(const float* __restrict__ tbuf,
              const u16* __restrict__ ogh, const u16* __restrict__ ogl,
              const u16* __restrict__ B2h, const u16* __restrict__ B2l,
              const float* __restrict__ sg4, const float* __restrict__ sg5,
              float* __restrict__ dst) {
    const int r0 = blockIdx.x * 32;
    __shared__ u16 Sh[32 * 256], Sl[32 * 256];
    {
        const int tid = threadIdx.x;
        const int row = tid >> 3, cb = (tid & 7) * 32;
#pragma unroll
        for (int u = 0; u < 4; ++u) {
            int colb = cb + u * 8;
            const float* t1 = tbuf + (size_t)(r0 + row) * 512 + colb;
            const float* t2 = t1 + 256;
            u16 hv8[8], lv8[8];
#pragma unroll
            for (int j2 = 0; j2 < 2; ++j2) {
                float4 x1 = *(const float4*)(t1 + j2 * 4);
                float4 x2 = *(const float4*)(t2 + j2 * 4);
                float sv[4];
                sv[0] = x1.x * sigm(x1.x) * x2.x;
                sv[1] = x1.y * sigm(x1.y) * x2.y;
                sv[2] = x1.z * sigm(x1.z) * x2.z;
                sv[3] = x1.w * sigm(x1.w) * x2.w;
#pragma unroll
                for (int j = 0; j < 4; ++j) {
                    u16 hh = f2bf(sv[j]);
                    hv8[j2 * 4 + j] = hh;
                    lv8[j2 * 4 + j] = f2bf(sv[j] - bf2f(hh));
                }
            }
            int g = (colb >> 3) ^ (row & 7);
            *(s8v*)(Sh + row * 256 + g * 8) = *(s8v*)hv8;
            *(s8v*)(Sl + row * 256 + g * 8) = *(s8v*)lv8;
        }
    }
    __syncthreads();
    const int l = threadIdx.x & 63, w = threadIdx.x >> 6;
    const int lr = l & 15, lq = l >> 4, kg = lq * 8;
    const int c0 = w * 32;
    f4v ac1[2][2] = {}, ac2[2][2] = {};
    // og part, K=128
#pragma unroll
    for (int ks = 0; ks < 4; ++ks) {
        s8v a0h = *(const s8v*)(ogh + (size_t)(r0 + lr) * 128 + ks * 32 + kg);
        s8v a1h = *(const s8v*)(ogh + (size_t)(r0 + 16 + lr) * 128 + ks * 32 + kg);
        s8v a0l = *(const s8v*)(ogl + (size_t)(r0 + lr) * 128 + ks * 32 + kg);
        s8v a1l = *(const s8v*)(ogl + (size_t)(r0 + 16 + lr) * 128 + ks * 32 + kg);
        s8v b0h = *(const s8v*)(B2h + (size_t)(c0 + lr) * 384 + ks * 32 + kg);
        s8v b1h = *(const s8v*)(B2h + (size_t)(c0 + 16 + lr) * 384 + ks * 32 + kg);
        s8v b0l = *(const s8v*)(B2l + (size_t)(c0 + lr) * 384 + ks * 32 + kg);
        s8v b1l = *(const s8v*)(B2l + (size_t)(c0 + 16 + lr) * 384 + ks * 32 + kg);
        ac1[0][0] = MFMA(a0h, b0h, ac1[0][0], 0, 0, 0); ac1[0][1] = MFMA(a0h, b1h, ac1[0][1], 0, 0, 0);
        ac1[1][0] = MFMA(a1h, b0h, ac1[1][0], 0, 0, 0); ac1[1][1] = MFMA(a1h, b1h, ac1[1][1], 0, 0, 0);
        ac1[0][0] = MFMA(a0h, b0l, ac1[0][0], 0, 0, 0); ac1[0][1] = MFMA(a0h, b1l, ac1[0][1], 0, 0, 0);
        ac1[1][0] = MFMA(a1h, b0l, ac1[1][0], 0, 0, 0); ac1[1][1] = MFMA(a1h, b1l, ac1[1][1], 0, 0, 0);
        ac1[0][0] = MFMA(a0l, b0h, ac1[0][0], 0, 0, 0); ac1[0][1] = MFMA(a0l, b1h, ac1[0][1], 0, 0, 0);
        ac1[1][0] = MFMA(a1l, b0h, ac1[1][0], 0, 0, 0); ac1[1][1] = MFMA(a1l, b1h, ac1[1][1], 0, 0, 0);
    }
    // swiglu part, K=256 from LDS
#pragma unroll
    for (int ks = 0; ks < 8; ++ks) {
        int g = (4 * ks + lq) ^ (lr & 7);
        s8v a0h = *(const s8v*)(Sh + lr * 256 + g * 8);
        s8v a1h = *(const s8v*)(Sh + (16 + lr) * 256 + g * 8);
        s8v a0l = *(const s8v*)(Sl + lr * 256 + g * 8);
        s8v a1l = *(const s8v*)(Sl + (16 + lr) * 256 + g * 8);
        s8v b0h = *(const s8v*)(B2h + (size_t)(c0 + lr) * 384 + 128 + ks * 32 + kg);
        s8v b1h = *(const s8v*)(B2h + (size_t)(c0 + 16 + lr) * 384 + 128 + ks * 32 + kg);
        s8v b0l = *(const s8v*)(B2l + (size_t)(c0 + lr) * 384 + 128 + ks * 32 + kg);
        s8v b1l = *(const s8v*)(B2l + (size_t)(c0 + 16 + lr) * 384 + 128 + ks * 32 + kg);
        ac2[0][0] = MFMA(a0h, b0h, ac2[0][0], 0, 0, 0); ac2[0][1] = MFMA(a0h, b1h, ac2[0][1], 0, 0, 0);
        ac2[1][0] = MFMA(a1h, b0h, ac2[1][0], 0, 0, 0); ac2[1][1] = MFMA(a1h, b1h, ac2[1][1], 0, 0, 0);
        ac2[0][0] = MFMA(a0h, b0l, ac2[0][0], 0, 0, 0); ac2[0][1] = MFMA(a0h, b1l, ac2[0][1], 0, 0, 0);
        ac2[1][0] = MFMA(a1h, b0l, ac2[1][0], 0, 0, 0); ac2[1][1] = MFMA(a1h, b1l, ac2[1][1], 0, 0, 0);
        ac2[0][0] = MFMA(a0l, b0h, ac2[0][0], 0, 0, 0); ac2[0][1] = MFMA(a0l, b1h, ac2[0][1], 0, 0, 0);
        ac2[1][0] = MFMA(a1l, b0h, ac2[1][0], 0, 0, 0); ac2[1][1] = MFMA(a1l, b1h, ac2[1][1], 0, 0, 0);
    }
#pragma unroll
    for (int mi = 0; mi < 2; ++mi)
#pragma unroll
        for (int i = 0; i < 4; ++i) {
            int row = r0 + mi * 16 + lq * 4 + i;
#pragma unroll
            for (int ni = 0; ni < 2; ++ni) {
                int col = c0 + ni * 16 + lr;
                size_t idx = (size_t)row * CD + col;
                dst[idx] = sg4[idx] * ac1[mi][ni][i] + sg5[idx] * ac2[mi][ni][i];
            }
        }
}

extern "C" void kernel_launch(void* const* d_in, const int* in_sizes, int n_in,
                              void* d_out, int out_size, void* d_ws, size_t ws_size,
                              hipStream_t stream) {
    const float* ql = (const float*)d_in[0];
    const float* cl = (const float*)d_in[1];
    const float* plm = (const float*)d_in[2];
    const float* atom_mask = (const float*)d_in[3];
    const float* attn_gamma = (const float*)d_in[4];
    const float* attn_wsig = (const float*)d_in[5];
    const float* attn_bsig = (const float*)d_in[6];
    const float* attn_wskip = (const float*)d_in[7];
    const float* wq = (const float*)d_in[8];
    const float* bq = (const float*)d_in[9];
    const float* wk = (const float*)d_in[10];
    const float* wv = (const float*)d_in[11];
    const float* lnz_g = (const float*)d_in[12];
    const float* lnz_b = (const float*)d_in[13];
    const float* w_pair = (const float*)d_in[14];
    const float* w_gate = (const float*)d_in[15];
    const float* w_out = (const float*)d_in[16];
    const float* w_ao = (const float*)d_in[17];
    const float* b_ao = (const float*)d_in[18];
    const float* tr_gamma = (const float*)d_in[19];
    const float* tr_wsig = (const float*)d_in[20];
    const float* tr_bsig = (const float*)d_in[21];
    const float* tr_wskip = (const float*)d_in[22];
    const float* w_t1 = (const float*)d_in[23];
    const float* w_t2 = (const float*)d_in[24];
    const float* w_t3 = (const float*)d_in[25];
    const float* w_to = (const float*)d_in[26];
    const float* b_to = (const float*)d_in[27];
    float* out = (float*)d_out;
    float* ws = (float*)d_ws;

    // fp32 region
    float* sg = ws;                   // 18 NC : [3][6][NC]
    float* tbuf = ws + 18 * NC;       // 4 NC : [N][512]
    float* pb = ws + 22 * NC;         // 12 NC : [3][64][4][32][128]
    float* a_buf = ws + 34 * NC;      // 1 NC
    float* Pbias = ws + 35 * NC;      // 2304 floats
    // u16 region
    u16* us = (u16*)(ws + 36 * NC);
    u16* qgh = us;                         // [N][512]
    u16* qgl = qgh + 4 * NC;
    u16* ogh = qgl + 4 * NC;               // [N][128]
    u16* ogl = ogh + NC;
    u16* vTh = ogl + NC;                   // [128][2048] + pad
    u16* vTl = vTh + NC + 128;
    u16* BP1h = vTl + NC + 128;
    u16* BP1l = BP1h + 294912;
    u16* BG1h = BP1l + 294912;
    u16* BG1l = BG1h + 393216;
    u16* BG2h = BG1l + 393216;
    u16* BG2l = BG2h + 147456;

    // State-independence insurance: every call starts from identical ws content.
    // (graph-capturable; ~47 MB ≈ 7 us at fill rates)
    size_t used_bytes = (size_t)36 * NC * 4 +
                        ((size_t)12 * NC + 256 + 2 * 294912 + 2 * 393216 + 2 * 147456) * 2;
    hipMemsetAsync(d_ws, 0, used_bytes, stream);

    prep_w<<<3273, 256, 0, stream>>>(attn_gamma, attn_wsig, attn_bsig, attn_wskip,
        wq, wk, wv, w_gate, w_out, w_ao, b_ao,
        tr_gamma, tr_wsig, tr_bsig, tr_wskip,
        w_t1, w_t2, w_t3, w_to, b_to,
        BP1h, BP1l, BG1h, BG1l, BG2h, BG2l, Pbias);
    pb_kernel<<<dim3(64, 16), 256, 0, stream>>>(plm, lnz_g, lnz_b, w_pair, pb);
    mf_p1f<<<dim3(64, 6, 3), 256, 0, stream>>>(cl, BP1h, BP1l, Pbias, sg);

    for (int i = 0; i < 3; ++i) {
        const float* a_cur = (i == 0) ? ql : a_buf;
        float* sgi = sg + (size_t)i * 6 * NC;
        k1_fused<<<dim3(64, 4), 256, 0, stream>>>(a_cur, sgi,
            BG1h + (size_t)i * 131072, BG1l + (size_t)i * 131072,
            bq + (size_t)i * 128, qgh, qgl, vTh, vTl, tbuf);
        attn_mfma<<<dim3(64, 4), 64, 0, stream>>>(qgh, qgl, vTh, vTl,
            pb + (size_t)i * 64 * 4 * 32 * 128, atom_mask, ogh, ogl);
        float* dst = (i == 2) ? out : a_buf;
        k3_fused<<<64, 256, 0, stream>>>(tbuf, ogh, ogl,
            BG2h + (size_t)i * 49152, BG2l + (size_t)i * 49152,
            sgi + 4 * NC, sgi + 5 * NC, dst);
    }
}

// Round 7
// 189.043 us; speedup vs baseline: 1.0112x; 1.0112x over previous
//
#include <hip/hip_runtime.h>
#include <math.h>

#define NA 2048
#define CD 128
#define NC ((size_t)262144)   // NA*CD

typedef unsigned short u16;
typedef short s8v __attribute__((ext_vector_type(8)));
typedef float f4v __attribute__((ext_vector_type(4)));
#define MFMA __builtin_amdgcn_mfma_f32_16x16x32_bf16

__device__ __forceinline__ float sigm(float x) { return 1.f / (1.f + __expf(-x)); }
__device__ __forceinline__ u16 f2bf(float x) {
    unsigned u = __float_as_uint(x);
    u += 0x7fffu + ((u >> 16) & 1u);
    return (u16)(u >> 16);
}
__device__ __forceinline__ float bf2f(u16 h) { return __uint_as_float((unsigned)h << 16); }

struct MegaP {
    const float *ql, *cl, *plm, *atom_mask;
    const float *attn_gamma, *attn_wsig, *attn_bsig, *attn_wskip;
    const float *wq, *bq, *wk, *wv, *lnz_g, *lnz_b, *w_pair, *w_gate, *w_out, *w_ao, *b_ao;
    const float *tr_gamma, *tr_wsig, *tr_bsig, *tr_wskip, *w_t1, *w_t2, *w_t3, *w_to, *b_to;
    float *out, *sg, *tbuf, *pb, *a_buf, *Pbias;
    u16 *qgh, *qgl, *ogh, *ogl, *vTh, *vTl, *BP1h, *BP1l, *BG1h, *BG1l, *BG2h, *BG2l;
};

// ======================= phase bodies =======================

__device__ __forceinline__ void dev_prep(const MegaP& P, int e) {
    if (e >= 835584) {
        int t = e - 835584;
        if (t < 2304) {
            int z = t / 768, rem = t % 768, j = rem >> 7, c = rem & 127;
            float v = 0.f;
            if (j == 0) v = P.attn_bsig[z * 128 + c];
            else if (j == 2) v = P.tr_bsig[z * 128 + c];
            else if (j == 4) v = P.b_ao[z * 128 + c];
            else if (j == 5) v = P.b_to[z * 128 + c];
            P.Pbias[t] = v;
        }
        return;
    }
    int z = e / 278528, r = e % 278528;
    float val;
    u16 *dh, *dl;
    size_t dofs;
    if (r < 98304) {
        int c = r >> 7, k = r & 127, seg = c >> 7, cc = c & 127;
        const float* w;
        const float* g = nullptr;
        switch (seg) {
            case 0: w = P.attn_wsig; g = P.attn_gamma; break;
            case 1: w = P.attn_wskip; g = P.attn_gamma; break;
            case 2: w = P.tr_wsig; g = P.tr_gamma; break;
            case 3: w = P.tr_wskip; g = P.tr_gamma; break;
            case 4: w = P.w_ao; break;
            default: w = P.w_to; break;
        }
        val = w[((size_t)z * 128 + k) * 128 + cc];
        if (g) val *= g[z * 128 + k];
        dh = P.BP1h; dl = P.BP1l; dofs = (size_t)z * 98304 + r;
    } else if (r < 229376) {
        int t = r - 98304, c = t >> 7, k = t & 127;
        if (c < 512) {
            int seg = c >> 7, cc = c & 127;
            const float* w = (seg == 0) ? P.wq : (seg == 1) ? P.wk : (seg == 2) ? P.wv : P.w_gate;
            val = w[((size_t)z * 128 + k) * 128 + cc];
        } else {
            int tt = c - 512;
            const float* w = (tt < 256) ? P.w_t1 : P.w_t2;
            val = w[(size_t)z * 32768 + (size_t)k * 256 + (tt & 255)];
        }
        dh = P.BG1h; dl = P.BG1l; dofs = (size_t)z * 131072 + t;
    } else {
        int t = r - 229376, c = t / 384, k = t % 384;
        val = (k < 128) ? P.w_out[((size_t)z * 128 + k) * 128 + c]
                        : P.w_t3[(size_t)z * 32768 + (size_t)(k - 128) * 128 + c];
        dh = P.BG2h; dl = P.BG2l; dofs = (size_t)z * 49152 + t;
    }
    u16 h = f2bf(val);
    dh[dofs] = h;
    dl[dofs] = f2bf(val - bf2f(h));
}

__device__ __forceinline__ void dev_pb_fold(const MegaP& P, float (*gw)[4][16], float (*c0s)[4], int tid) {
    if (tid < 12) {
        int i = tid >> 2, h = tid & 3;
        float c = 0.f;
        for (int cp = 0; cp < 16; ++cp) {
            float wp = P.w_pair[(i * 16 + cp) * 4 + h];
            gw[i][h][cp] = P.lnz_g[i * 16 + cp] * wp;
            c += P.lnz_b[i * 16 + cp] * wp;
        }
        c0s[i][h] = c;
    }
}

__device__ __forceinline__ void dev_pb(const MegaP& P, float (*gw)[4][16], float (*c0s)[4],
                                       int c, int yy, int tid) {
    int p = yy * 256 + tid;
    int ql_ = p >> 7, kl = p & 127;
    int kstart = max(0, c * 32 - 48), kend = min(2048, c * 32 + 80);
    int k = kstart + kl;
    if (k >= kend) {
#pragma unroll
        for (int i = 0; i < 3; ++i)
#pragma unroll
            for (int h = 0; h < 4; ++h)
                P.pb[((((size_t)i * 64 + c) * 4 + h) * 32 + ql_) * 128 + kl] = 0.f;
        return;
    }
    int q = c * 32 + ql_;
    const float* row = P.plm + ((size_t)q * 2048 + (size_t)k) * 16;
    float x[16];
#pragma unroll
    for (int j = 0; j < 4; ++j) {
        float4 v = *(const float4*)(row + j * 4);
        x[j * 4 + 0] = v.x; x[j * 4 + 1] = v.y; x[j * 4 + 2] = v.z; x[j * 4 + 3] = v.w;
    }
    float s = 0.f, sq = 0.f;
#pragma unroll
    for (int cp = 0; cp < 16; ++cp) { s += x[cp]; sq += x[cp] * x[cp]; }
    float mean = s * (1.f / 16.f);
    float var = sq * (1.f / 16.f) - mean * mean;
    float r = 1.f / sqrtf(var + 1e-5f);
    float xn[16];
#pragma unroll
    for (int cp = 0; cp < 16; ++cp) xn[cp] = (x[cp] - mean) * r;
#pragma unroll
    for (int i = 0; i < 3; ++i)
#pragma unroll
        for (int h = 0; h < 4; ++h) {
            float d = c0s[i][h];
#pragma unroll
            for (int cp = 0; cp < 16; ++cp) d = fmaf(xn[cp], gw[i][h][cp], d);
            P.pb[((((size_t)i * 64 + c) * 4 + h) * 32 + ql_) * 128 + kl] = d;
        }
}

// p1f task: LN/copy of cl rows -> LDS -> GEMM chunk -> sg. Contains __syncthreads.
__device__ __forceinline__ void dev_p1f(const MegaP& P, int x_, int chunk, int z, int tid,
                                        u16* Ah, u16* Al) {
    const int r0 = x_ * 32;
    {
        const int row = tid >> 3, cb = (tid & 7) * 16;
        const float* ar = P.cl + (size_t)(r0 + row) * CD + cb;
        float x[16];
#pragma unroll
        for (int j = 0; j < 4; ++j) {
            float4 v = *(const float4*)(ar + j * 4);
            x[4 * j] = v.x; x[4 * j + 1] = v.y; x[4 * j + 2] = v.z; x[4 * j + 3] = v.w;
        }
        float s = 0.f, sq = 0.f;
#pragma unroll
        for (int j = 0; j < 16; ++j) { s += x[j]; sq += x[j] * x[j]; }
#pragma unroll
        for (int m = 1; m < 8; m <<= 1) { s += __shfl_xor(s, m); sq += __shfl_xor(sq, m); }
        float mean = s * (1.f / 128.f), var = sq * (1.f / 128.f) - mean * mean;
        float rr = 1.f / sqrtf(var + 1e-5f);
#pragma unroll
        for (int gp = 0; gp < 2; ++gp) {
            u16 hv8[8], lv8[8];
#pragma unroll
            for (int j = 0; j < 8; ++j) {
                float xv = x[gp * 8 + j];
                float val = (chunk < 4) ? (xv - mean) * rr : xv;
                u16 hh = f2bf(val);
                hv8[j] = hh; lv8[j] = f2bf(val - bf2f(hh));
            }
            int g = ((cb >> 3) + gp) ^ (row & 7);
            *(s8v*)(Ah + row * 128 + g * 8) = *(s8v*)hv8;
            *(s8v*)(Al + row * 128 + g * 8) = *(s8v*)lv8;
        }
    }
    __syncthreads();
    const int l = tid & 63, wv_ = tid >> 6;
    const int lr = l & 15, lq = l >> 4, kg = lq * 8;
    const int c0 = wv_ * 32;
    const u16* Bh = P.BP1h + (size_t)z * 98304 + (size_t)chunk * 16384;
    const u16* Bl = P.BP1l + (size_t)z * 98304 + (size_t)chunk * 16384;
    f4v acc[2][2] = {};
#pragma unroll
    for (int ks = 0; ks < 4; ++ks) {
        int g = (4 * ks + lq) ^ (lr & 7);
        s8v a0h = *(const s8v*)(Ah + lr * 128 + g * 8);
        s8v a1h = *(const s8v*)(Ah + (16 + lr) * 128 + g * 8);
        s8v a0l = *(const s8v*)(Al + lr * 128 + g * 8);
        s8v a1l = *(const s8v*)(Al + (16 + lr) * 128 + g * 8);
        s8v b0h = *(const s8v*)(Bh + (size_t)(c0 + lr) * 128 + ks * 32 + kg);
        s8v b1h = *(const s8v*)(Bh + (size_t)(c0 + 16 + lr) * 128 + ks * 32 + kg);
        s8v b0l = *(const s8v*)(Bl + (size_t)(c0 + lr) * 128 + ks * 32 + kg);
        s8v b1l = *(const s8v*)(Bl + (size_t)(c0 + 16 + lr) * 128 + ks * 32 + kg);
        acc[0][0] = MFMA(a0h, b0h, acc[0][0], 0, 0, 0); acc[0][1] = MFMA(a0h, b1h, acc[0][1], 0, 0, 0);
        acc[1][0] = MFMA(a1h, b0h, acc[1][0], 0, 0, 0); acc[1][1] = MFMA(a1h, b1h, acc[1][1], 0, 0, 0);
        acc[0][0] = MFMA(a0h, b0l, acc[0][0], 0, 0, 0); acc[0][1] = MFMA(a0h, b1l, acc[0][1], 0, 0, 0);
        acc[1][0] = MFMA(a1h, b0l, acc[1][0], 0, 0, 0); acc[1][1] = MFMA(a1h, b1l, acc[1][1], 0, 0, 0);
        acc[0][0] = MFMA(a0l, b0h, acc[0][0], 0, 0, 0); acc[0][1] = MFMA(a0l, b1h, acc[0][1], 0, 0, 0);
        acc[1][0] = MFMA(a1l, b0h, acc[1][0], 0, 0, 0); acc[1][1] = MFMA(a1l, b1h, acc[1][1], 0, 0, 0);
    }
    const bool dosig = (chunk != 1) && (chunk != 3);
    const float* bp = P.Pbias + (z * 6 + chunk) * 128;
    float* dst = P.sg + ((size_t)z * 6 + chunk) * NC;
#pragma unroll
    for (int mi = 0; mi < 2; ++mi)
#pragma unroll
        for (int i = 0; i < 4; ++i) {
            int row = r0 + mi * 16 + lq * 4 + i;
#pragma unroll
            for (int ni = 0; ni < 2; ++ni) {
                int col = c0 + ni * 16 + lr;
                float xx = acc[mi][ni][i];
                if (dosig) xx = sigm(xx + bp[col]);
                dst[(size_t)row * CD + col] = xx;
            }
        }
    __syncthreads();
}

// k1 task: fused adaLN + QKVG/t1t2 GEMM for (r0, y). Contains __syncthreads.
__device__ __forceinline__ void dev_k1(const MegaP& P, int ib, int r0, int y, int tid,
                                       u16* Ah, u16* Al) {
    const float* a_cur = (ib == 0) ? P.ql : P.a_buf;
    const float* sgi = P.sg + (size_t)ib * 6 * NC;
    const u16* B1h = P.BG1h + (size_t)ib * 131072;
    const u16* B1l = P.BG1l + (size_t)ib * 131072;
    const float* bqz = P.bq + (size_t)ib * 128;
    {
        const int row = tid >> 3, cb = (tid & 7) * 16;
        const float* ar = a_cur + (size_t)(r0 + row) * CD + cb;
        float x[16];
#pragma unroll
        for (int j = 0; j < 4; ++j) {
            float4 v = *(const float4*)(ar + j * 4);
            x[4 * j] = v.x; x[4 * j + 1] = v.y; x[4 * j + 2] = v.z; x[4 * j + 3] = v.w;
        }
        float s = 0.f, sq = 0.f;
#pragma unroll
        for (int j = 0; j < 16; ++j) { s += x[j]; sq += x[j] * x[j]; }
#pragma unroll
        for (int m = 1; m < 8; m <<= 1) { s += __shfl_xor(s, m); sq += __shfl_xor(sq, m); }
        float mean = s * (1.f / 128.f), var = sq * (1.f / 128.f) - mean * mean;
        float rr = 1.f / sqrtf(var + 1e-5f);
        const float* sig = sgi + ((y < 2) ? 0 : 2 * NC) + (size_t)(r0 + row) * CD + cb;
        const float* skp = sgi + ((y < 2) ? NC : 3 * NC) + (size_t)(r0 + row) * CD + cb;
#pragma unroll
        for (int gp = 0; gp < 2; ++gp) {
            u16 hv8[8], lv8[8];
#pragma unroll
            for (int j = 0; j < 8; ++j) {
                int jj = gp * 8 + j;
                float ln = (x[jj] - mean) * rr;
                float val = fmaf(sig[jj], ln, skp[jj]);
                u16 hh = f2bf(val);
                hv8[j] = hh; lv8[j] = f2bf(val - bf2f(hh));
            }
            int g = ((cb >> 3) + gp) ^ (row & 7);
            *(s8v*)(Ah + row * 128 + g * 8) = *(s8v*)hv8;
            *(s8v*)(Al + row * 128 + g * 8) = *(s8v*)lv8;
        }
    }
    __syncthreads();
    const int l = tid & 63, wv_ = tid >> 6;
    const int lr = l & 15, lq = l >> 4, kg = lq * 8;
    const int chunk = 2 * y + (wv_ >> 1);
    const int cbase = (wv_ & 1) * 64;
    f4v acc[2][2][2] = {};
#pragma unroll
    for (int ks = 0; ks < 4; ++ks) {
        int g = (4 * ks + lq) ^ (lr & 7);
        s8v a0h = *(const s8v*)(Ah + lr * 128 + g * 8);
        s8v a1h = *(const s8v*)(Ah + (16 + lr) * 128 + g * 8);
        s8v a0l = *(const s8v*)(Al + lr * 128 + g * 8);
        s8v a1l = *(const s8v*)(Al + (16 + lr) * 128 + g * 8);
#pragma unroll
        for (int t2 = 0; t2 < 2; ++t2) {
            int crow = chunk * 128 + cbase + t2 * 32;
            s8v b0h = *(const s8v*)(B1h + (size_t)(crow + lr) * 128 + ks * 32 + kg);
            s8v b1h = *(const s8v*)(B1h + (size_t)(crow + 16 + lr) * 128 + ks * 32 + kg);
            s8v b0l = *(const s8v*)(B1l + (size_t)(crow + lr) * 128 + ks * 32 + kg);
            s8v b1l = *(const s8v*)(B1l + (size_t)(crow + 16 + lr) * 128 + ks * 32 + kg);
            acc[t2][0][0] = MFMA(a0h, b0h, acc[t2][0][0], 0, 0, 0);
            acc[t2][0][1] = MFMA(a0h, b1h, acc[t2][0][1], 0, 0, 0);
            acc[t2][1][0] = MFMA(a1h, b0h, acc[t2][1][0], 0, 0, 0);
            acc[t2][1][1] = MFMA(a1h, b1h, acc[t2][1][1], 0, 0, 0);
            acc[t2][0][0] = MFMA(a0h, b0l, acc[t2][0][0], 0, 0, 0);
            acc[t2][0][1] = MFMA(a0h, b1l, acc[t2][0][1], 0, 0, 0);
            acc[t2][1][0] = MFMA(a1h, b0l, acc[t2][1][0], 0, 0, 0);
            acc[t2][1][1] = MFMA(a1h, b1l, acc[t2][1][1], 0, 0, 0);
            acc[t2][0][0] = MFMA(a0l, b0h, acc[t2][0][0], 0, 0, 0);
            acc[t2][0][1] = MFMA(a0l, b1h, acc[t2][0][1], 0, 0, 0);
            acc[t2][1][0] = MFMA(a1l, b0h, acc[t2][1][0], 0, 0, 0);
            acc[t2][1][1] = MFMA(a1l, b1h, acc[t2][1][1], 0, 0, 0);
        }
    }
#pragma unroll
    for (int t2 = 0; t2 < 2; ++t2)
#pragma unroll
        for (int mi = 0; mi < 2; ++mi)
#pragma unroll
            for (int i = 0; i < 4; ++i) {
                int row = r0 + mi * 16 + lq * 4 + i;
#pragma unroll
                for (int ni = 0; ni < 2; ++ni) {
                    int gcol = chunk * 128 + cbase + t2 * 32 + ni * 16 + lr;
                    float x = acc[t2][mi][ni][i];
                    if (chunk == 0) x += bqz[gcol];
                    if (gcol < 512) {
                        u16 hh = f2bf(x), ll = f2bf(x - bf2f(hh));
                        P.qgh[(size_t)row * 512 + gcol] = hh;
                        P.qgl[(size_t)row * 512 + gcol] = ll;
                        if (chunk == 2) {
                            int cv = gcol - 256;
                            P.vTh[(size_t)cv * 2048 + row] = hh;
                            P.vTl[(size_t)cv * 2048 + row] = ll;
                        }
                    } else {
                        P.tbuf[(size_t)row * 512 + (gcol - 512)] = x;
                    }
                }
            }
    __syncthreads();
}

// attn task for (c,h); P stored hi+lo in LDS (2-term PV). Contains __syncthreads.
__device__ __forceinline__ void dev_attn(const MegaP& P, int ib, int c, int h,
                                         int tid, bool act, int mi, u16* Pls, u16* Pll) {
    const int l = tid & 63;
    const int kstart = max(0, c * 32 - 48);
    const int kend = min(2048, c * 32 + 80);
    const int nk = kend - kstart;
    const int lr = l & 15, lq = l >> 4, kg = lq * 8;
    const float* pbp = P.pb + (size_t)ib * 4 * NC + (size_t)((c * 4 + h) * 32) * 128;
    f4v oac[2] = {};
    float inv_s[4];
    if (act) {
        s8v qfh, qfl;
        {
            size_t qb = (size_t)(c * 32 + mi * 16 + lr) * 512 + h * 32 + kg;
            qfh = *(const s8v*)(P.qgh + qb);
            qfl = *(const s8v*)(P.qgl + qb);
        }
        f4v lac[8] = {};
#pragma unroll
        for (int kt = 0; kt < 8; ++kt) {
            int krow = min(kstart + kt * 16 + lr, 2047);
            size_t kb = (size_t)krow * 512 + 128 + h * 32 + kg;
            s8v bh = *(const s8v*)(P.qgh + kb);
            s8v bl = *(const s8v*)(P.qgl + kb);
            lac[kt] = MFMA(qfh, bh, lac[kt], 0, 0, 0);
            lac[kt] = MFMA(qfh, bl, lac[kt], 0, 0, 0);
            lac[kt] = MFMA(qfl, bh, lac[kt], 0, 0, 0);
        }
        float mb8[8];
#pragma unroll
        for (int kt = 0; kt < 8; ++kt) {
            int kl = kt * 16 + lr;
            mb8[kt] = (kl < nk) ? (P.atom_mask[kstart + kl] - 1.f) * 1.0e9f : 0.f;
        }
        const float scale = 0.17677669529663687f;
#pragma unroll
        for (int i = 0; i < 4; ++i) {
            const int rl = mi * 16 + lq * 4 + i;
            float lg[8];
#pragma unroll
            for (int kt = 0; kt < 8; ++kt) {
                int kl = kt * 16 + lr;
                float v = -1e30f;
                if (kl < nk) v = fmaf(lac[kt][i], scale, pbp[(size_t)rl * 128 + kl] + mb8[kt]);
                lg[kt] = v;
            }
            float m = lg[0];
#pragma unroll
            for (int kt = 1; kt < 8; ++kt) m = fmaxf(m, lg[kt]);
#pragma unroll
            for (int msk = 1; msk < 16; msk <<= 1) m = fmaxf(m, __shfl_xor(m, msk));
            float ssum = 0.f;
#pragma unroll
            for (int kt = 0; kt < 8; ++kt) {
                float p = __expf(lg[kt] - m);
                ssum += p;
                u16 p16 = f2bf(p);
                int kl = kt * 16 + lr;
                int g = (kl >> 3) ^ (rl & 7);
                Pls[rl * 128 + g * 8 + (kl & 7)] = p16;
                Pll[rl * 128 + g * 8 + (kl & 7)] = f2bf(p - bf2f(p16));
            }
#pragma unroll
            for (int msk = 1; msk < 16; msk <<= 1) ssum += __shfl_xor(ssum, msk);
            inv_s[i] = 1.f / ssum;
        }
    }
    __syncthreads();   // P tiles fully in LDS before vector re-read
    if (act) {
#pragma unroll
        for (int ks = 0; ks < 4; ++ks) {
            int prow = mi * 16 + lr;
            int g = (4 * ks + lq) ^ (prow & 7);
            s8v pA = *(const s8v*)(Pls + prow * 128 + g * 8);
            s8v pAl = *(const s8v*)(Pll + prow * 128 + g * 8);
            int kcol = kstart + ks * 32 + kg;
            if (kcol > 2040) kcol = 0;   // clamped slots have P == 0 exactly
#pragma unroll
            for (int ct = 0; ct < 2; ++ct) {
                size_t vb = (size_t)(h * 32 + ct * 16 + lr) * 2048 + kcol;
                s8v vh = *(const s8v*)(P.vTh + vb);
                s8v vl = *(const s8v*)(P.vTl + vb);
                oac[ct] = MFMA(pA, vh, oac[ct], 0, 0, 0);
                oac[ct] = MFMA(pA, vl, oac[ct], 0, 0, 0);
                oac[ct] = MFMA(pAl, vh, oac[ct], 0, 0, 0);
            }
        }
#pragma unroll
        for (int ct = 0; ct < 2; ++ct)
#pragma unroll
            for (int i = 0; i < 4; ++i) {
                int rl = mi * 16 + lq * 4 + i;
                int row = c * 32 + rl;
                int d = ct * 16 + lr;
                float o = oac[ct][i] * inv_s[i];
                size_t gidx = (size_t)row * 512 + 384 + h * 32 + d;
                float g = bf2f(P.qgh[gidx]) + bf2f(P.qgl[gidx]);
                float v = o * sigm(g);
                u16 hh = f2bf(v);
                size_t oi = (size_t)row * 128 + h * 32 + d;
                P.ogh[oi] = hh;
                P.ogl[oi] = f2bf(v - bf2f(hh));
            }
    }
}

// k3 task for r0. Contains __syncthreads.
__device__ __forceinline__ void dev_k3(const MegaP& P, int ib, int r0, int tid,
                                       u16* Sh, u16* Sl) {
    const u16* B2h = P.BG2h + (size_t)ib * 49152;
    const u16* B2l = P.BG2l + (size_t)ib * 49152;
    const float* sg4 = P.sg + (size_t)ib * 6 * NC + 4 * NC;
    const float* sg5 = P.sg + (size_t)ib * 6 * NC + 5 * NC;
    float* dst = (ib == 2) ? P.out : P.a_buf;
    {
        const int row = tid >> 3, cb = (tid & 7) * 32;
#pragma unroll
        for (int u = 0; u < 4; ++u) {
            int colb = cb + u * 8;
            const float* t1 = P.tbuf + (size_t)(r0 + row) * 512 + colb;
            const float* t2 = t1 + 256;
            u16 hv8[8], lv8[8];
#pragma unroll
            for (int j2 = 0; j2 < 2; ++j2) {
                float4 x1 = *(const float4*)(t1 + j2 * 4);
                float4 x2 = *(const float4*)(t2 + j2 * 4);
                float sv[4];
                sv[0] = x1.x * sigm(x1.x) * x2.x;
                sv[1] = x1.y * sigm(x1.y) * x2.y;
                sv[2] = x1.z * sigm(x1.z) * x2.z;
                sv[3] = x1.w * sigm(x1.w) * x2.w;
#pragma unroll
                for (int j = 0; j < 4; ++j) {
                    u16 hh = f2bf(sv[j]);
                    hv8[j2 * 4 + j] = hh;
                    lv8[j2 * 4 + j] = f2bf(sv[j] - bf2f(hh));
                }
            }
            int g = (colb >> 3) ^ (row & 7);
            *(s8v*)(Sh + row * 256 + g * 8) = *(s8v*)hv8;
            *(s8v*)(Sl + row * 256 + g * 8) = *(s8v*)lv8;
        }
    }
    __syncthreads();
    const int l = tid & 63, wv_ = tid >> 6;
    const int lr = l & 15, lq = l >> 4, kg = lq * 8;
    const int c0 = wv_ * 32;
    f4v ac1[2][2] = {}, ac2[2][2] = {};
#pragma unroll
    for (int ks = 0; ks < 4; ++ks) {
        s8v a0h = *(const s8v*)(P.ogh + (size_t)(r0 + lr) * 128 + ks * 32 + kg);
        s8v a1h = *(const s8v*)(P.ogh + (size_t)(r0 + 16 + lr) * 128 + ks * 32 + kg);
        s8v a0l = *(const s8v*)(P.ogl + (size_t)(r0 + lr) * 128 + ks * 32 + kg);
        s8v a1l = *(const s8v*)(P.ogl + (size_t)(r0 + 16 + lr) * 128 + ks * 32 + kg);
        s8v b0h = *(const s8v*)(B2h + (size_t)(c0 + lr) * 384 + ks * 32 + kg);
        s8v b1h = *(const s8v*)(B2h + (size_t)(c0 + 16 + lr) * 384 + ks * 32 + kg);
        s8v b0l = *(const s8v*)(B2l + (size_t)(c0 + lr) * 384 + ks * 32 + kg);
        s8v b1l = *(const s8v*)(B2l + (size_t)(c0 + 16 + lr) * 384 + ks * 32 + kg);
        ac1[0][0] = MFMA(a0h, b0h, ac1[0][0], 0, 0, 0); ac1[0][1] = MFMA(a0h, b1h, ac1[0][1], 0, 0, 0);
        ac1[1][0] = MFMA(a1h, b0h, ac1[1][0], 0, 0, 0); ac1[1][1] = MFMA(a1h, b1h, ac1[1][1], 0, 0, 0);
        ac1[0][0] = MFMA(a0h, b0l, ac1[0][0], 0, 0, 0); ac1[0][1] = MFMA(a0h, b1l, ac1[0][1], 0, 0, 0);
        ac1[1][0] = MFMA(a1h, b0l, ac1[1][0], 0, 0, 0); ac1[1][1] = MFMA(a1h, b1l, ac1[1][1], 0, 0, 0);
        ac1[0][0] = MFMA(a0l, b0h, ac1[0][0], 0, 0, 0); ac1[0][1] = MFMA(a0l, b1h, ac1[0][1], 0, 0, 0);
        ac1[1][0] = MFMA(a1l, b0h, ac1[1][0], 0, 0, 0); ac1[1][1] = MFMA(a1l, b1h, ac1[1][1], 0, 0, 0);
    }
#pragma unroll
    for (int ks = 0; ks < 8; ++ks) {
        int g = (4 * ks + lq) ^ (lr & 7);
        s8v a0h = *(const s8v*)(Sh + lr * 256 + g * 8);
        s8v a1h = *(const s8v*)(Sh + (16 + lr) * 256 + g * 8);
        s8v a0l = *(const s8v*)(Sl + lr * 256 + g * 8);
        s8v a1l = *(const s8v*)(Sl + (16 + lr) * 256 + g * 8);
        s8v b0h = *(const s8v*)(B2h + (size_t)(c0 + lr) * 384 + 128 + ks * 32 + kg);
        s8v b1h = *(const s8v*)(B2h + (size_t)(c0 + 16 + lr) * 384 + 128 + ks * 32 + kg);
        s8v b0l = *(const s8v*)(B2l + (size_t)(c0 + lr) * 384 + 128 + ks * 32 + kg);
        s8v b1l = *(const s8v*)(B2l + (size_t)(c0 + 16 + lr) * 384 + 128 + ks * 32 + kg);
        ac2[0][0] = MFMA(a0h, b0h, ac2[0][0], 0, 0, 0); ac2[0][1] = MFMA(a0h, b1h, ac2[0][1], 0, 0, 0);
        ac2[1][0] = MFMA(a1h, b0h, ac2[1][0], 0, 0, 0); ac2[1][1] = MFMA(a1h, b1h, ac2[1][1], 0, 0, 0);
        ac2[0][0] = MFMA(a0h, b0l, ac2[0][0], 0, 0, 0); ac2[0][1] = MFMA(a0h, b1l, ac2[0][1], 0, 0, 0);
        ac2[1][0] = MFMA(a1h, b0l, ac2[1][0], 0, 0, 0); ac2[1][1] = MFMA(a1h, b1l, ac2[1][1], 0, 0, 0);
        ac2[0][0] = MFMA(a0l, b0h, ac2[0][0], 0, 0, 0); ac2[0][1] = MFMA(a0l, b1h, ac2[0][1], 0, 0, 0);
        ac2[1][0] = MFMA(a1l, b0h, ac2[1][0], 0, 0, 0); ac2[1][1] = MFMA(a1l, b1h, ac2[1][1], 0, 0, 0);
    }
#pragma unroll
    for (int mi = 0; mi < 2; ++mi)
#pragma unroll
        for (int i = 0; i < 4; ++i) {
            int row = r0 + mi * 16 + lq * 4 + i;
#pragma unroll
            for (int ni = 0; ni < 2; ++ni) {
                int col = c0 + ni * 16 + lr;
                size_t idx = (size_t)row * CD + col;
                dst[idx] = sg4[idx] * ac1[mi][ni][i] + sg5[idx] * ac2[mi][ni][i];
            }
        }
    __syncthreads();
}

// ======================= kernels =======================

__global__ __launch_bounds__(256) void prep_w_k(MegaP P) {
    dev_prep(P, blockIdx.x * 256 + threadIdx.x);
}

// blocks [0,1152): p1f task; blocks [1152, 2176): pb task
__global__ __launch_bounds__(256) void combo_pp(MegaP P) {
    int bx = blockIdx.x;
    if (bx < 1152) {
        __shared__ u16 Ah[32 * 128], Al[32 * 128];
        int x_ = bx & 63, rem = bx >> 6;
        dev_p1f(P, x_, rem % 6, rem / 6, threadIdx.x, Ah, Al);
    } else {
        __shared__ float gw[3][4][16];
        __shared__ float c0s[3][4];
        dev_pb_fold(P, gw, c0s, threadIdx.x);
        __syncthreads();
        int pt = bx - 1152;
        dev_pb(P, gw, c0s, pt & 63, pt >> 6, threadIdx.x);
    }
}

__global__ __launch_bounds__(256) void k1_k(MegaP P, int ib) {
    __shared__ u16 Ah[32 * 128], Al[32 * 128];
    dev_k1(P, ib, blockIdx.x * 32, blockIdx.y, threadIdx.x, Ah, Al);
}

__global__ __launch_bounds__(128) void attn_k(MegaP P, int ib) {
    __shared__ u16 Pls[32 * 128], Pll[32 * 128];
    dev_attn(P, ib, blockIdx.x, blockIdx.y, threadIdx.x, true, threadIdx.x >> 6, Pls, Pll);
}

__global__ __launch_bounds__(256) void k3_k(MegaP P, int ib) {
    __shared__ u16 Sh[32 * 256], Sl[32 * 256];
    dev_k3(P, ib, blockIdx.x * 32, threadIdx.x, Sh, Sl);
}

extern "C" void kernel_launch(void* const* d_in, const int* in_sizes, int n_in,
                              void* d_out, int out_size, void* d_ws, size_t ws_size,
                              hipStream_t stream) {
    float* ws = (float*)d_ws;

    MegaP P;
    P.ql = (const float*)d_in[0];
    P.cl = (const float*)d_in[1];
    P.plm = (const float*)d_in[2];
    P.atom_mask = (const float*)d_in[3];
    P.attn_gamma = (const float*)d_in[4];
    P.attn_wsig = (const float*)d_in[5];
    P.attn_bsig = (const float*)d_in[6];
    P.attn_wskip = (const float*)d_in[7];
    P.wq = (const float*)d_in[8];
    P.bq = (const float*)d_in[9];
    P.wk = (const float*)d_in[10];
    P.wv = (const float*)d_in[11];
    P.lnz_g = (const float*)d_in[12];
    P.lnz_b = (const float*)d_in[13];
    P.w_pair = (const float*)d_in[14];
    P.w_gate = (const float*)d_in[15];
    P.w_out = (const float*)d_in[16];
    P.w_ao = (const float*)d_in[17];
    P.b_ao = (const float*)d_in[18];
    P.tr_gamma = (const float*)d_in[19];
    P.tr_wsig = (const float*)d_in[20];
    P.tr_bsig = (const float*)d_in[21];
    P.tr_wskip = (const float*)d_in[22];
    P.w_t1 = (const float*)d_in[23];
    P.w_t2 = (const float*)d_in[24];
    P.w_t3 = (const float*)d_in[25];
    P.w_to = (const float*)d_in[26];
    P.b_to = (const float*)d_in[27];
    P.out = (float*)d_out;

    P.sg = ws;                        // 18 NC
    P.tbuf = ws + 18 * NC;            // 4 NC
    P.pb = ws + 22 * NC;              // 12 NC
    P.a_buf = ws + 34 * NC;           // 1 NC
    P.Pbias = ws + 35 * NC;           // 2304 floats
    u16* us = (u16*)(ws + 36 * NC);
    P.qgh = us;
    P.qgl = P.qgh + 4 * NC;
    P.ogh = P.qgl + 4 * NC;
    P.ogl = P.ogh + NC;
    P.vTh = P.ogl + NC;
    P.vTl = P.vTh + NC + 128;
    P.BP1h = P.vTl + NC + 128;
    P.BP1l = P.BP1h + 294912;
    P.BG1h = P.BP1l + 294912;
    P.BG1l = P.BG1h + 393216;
    P.BG2h = P.BG1l + 393216;
    P.BG2l = P.BG2h + 147456;

    // state-independence insurance: identical ws content at the start of every call
    size_t used_bytes = (size_t)36 * NC * 4 +
                        ((size_t)12 * NC + 256 + 2 * 294912 + 2 * 393216 + 2 * 147456) * 2;
    hipMemsetAsync(d_ws, 0, used_bytes, stream);

    prep_w_k<<<3273, 256, 0, stream>>>(P);
    combo_pp<<<2176, 256, 0, stream>>>(P);
    for (int ib = 0; ib < 3; ++ib) {
        k1_k<<<dim3(64, 4), 256, 0, stream>>>(P, ib);
        attn_k<<<dim3(64, 4), 128, 0, stream>>>(P, ib);
        k3_k<<<64, 256, 0, stream>>>(P, ib);
    }
}

// Round 8
// 174.952 us; speedup vs baseline: 1.0926x; 1.0805x over previous
//
#include <hip/hip_runtime.h>
#include <math.h>

#define NA 2048
#define CD 128
#define NC ((size_t)262144)   // NA*CD

typedef unsigned short u16;
typedef short s8v __attribute__((ext_vector_type(8)));
typedef float f4v __attribute__((ext_vector_type(4)));
#define MFMA __builtin_amdgcn_mfma_f32_16x16x32_bf16

__device__ __forceinline__ float sigm(float x) { return 1.f / (1.f + __expf(-x)); }
__device__ __forceinline__ u16 f2bf(float x) {
    unsigned u = __float_as_uint(x);
    u += 0x7fffu + ((u >> 16) & 1u);
    return (u16)(u >> 16);
}
__device__ __forceinline__ float bf2f(u16 h) { return __uint_as_float((unsigned)h << 16); }

struct MegaP {
    const float *ql, *cl, *plm, *atom_mask;
    const float *attn_gamma, *attn_wsig, *attn_bsig, *attn_wskip;
    const float *wq, *bq, *wk, *wv, *lnz_g, *lnz_b, *w_pair, *w_gate, *w_out, *w_ao, *b_ao;
    const float *tr_gamma, *tr_wsig, *tr_bsig, *tr_wskip, *w_t1, *w_t2, *w_t3, *w_to, *b_to;
    float *out, *sg, *tbuf, *pb, *a_buf, *Pbias;
    u16 *qgh, *qgl, *ogh, *ogl, *vTh, *vTl, *BP1h, *BP1l, *BG1h, *BG1l, *BG2h, *BG2l;
};

// ======================= phase bodies =======================

__device__ __forceinline__ void dev_prep(const MegaP& P, int e) {
    if (e >= 835584) {
        int t = e - 835584;
        if (t < 2304) {
            int z = t / 768, rem = t % 768, j = rem >> 7, c = rem & 127;
            float v = 0.f;
            if (j == 0) v = P.attn_bsig[z * 128 + c];
            else if (j == 2) v = P.tr_bsig[z * 128 + c];
            else if (j == 4) v = P.b_ao[z * 128 + c];
            else if (j == 5) v = P.b_to[z * 128 + c];
            P.Pbias[t] = v;
        }
        return;
    }
    int z = e / 278528, r = e % 278528;
    float val;
    u16 *dh, *dl;
    size_t dofs;
    if (r < 98304) {
        int c = r >> 7, k = r & 127, seg = c >> 7, cc = c & 127;
        const float* w;
        const float* g = nullptr;
        switch (seg) {
            case 0: w = P.attn_wsig; g = P.attn_gamma; break;
            case 1: w = P.attn_wskip; g = P.attn_gamma; break;
            case 2: w = P.tr_wsig; g = P.tr_gamma; break;
            case 3: w = P.tr_wskip; g = P.tr_gamma; break;
            case 4: w = P.w_ao; break;
            default: w = P.w_to; break;
        }
        val = w[((size_t)z * 128 + k) * 128 + cc];
        if (g) val *= g[z * 128 + k];
        dh = P.BP1h; dl = P.BP1l; dofs = (size_t)z * 98304 + r;
    } else if (r < 229376) {
        int t = r - 98304, c = t >> 7, k = t & 127;
        if (c < 512) {
            int seg = c >> 7, cc = c & 127;
            const float* w = (seg == 0) ? P.wq : (seg == 1) ? P.wk : (seg == 2) ? P.wv : P.w_gate;
            val = w[((size_t)z * 128 + k) * 128 + cc];
        } else {
            int tt = c - 512;
            const float* w = (tt < 256) ? P.w_t1 : P.w_t2;
            val = w[(size_t)z * 32768 + (size_t)k * 256 + (tt & 255)];
        }
        dh = P.BG1h; dl = P.BG1l; dofs = (size_t)z * 131072 + t;
    } else {
        int t = r - 229376, c = t / 384, k = t % 384;
        val = (k < 128) ? P.w_out[((size_t)z * 128 + k) * 128 + c]
                        : P.w_t3[(size_t)z * 32768 + (size_t)(k - 128) * 128 + c];
        dh = P.BG2h; dl = P.BG2l; dofs = (size_t)z * 49152 + t;
    }
    u16 h = f2bf(val);
    dh[dofs] = h;
    dl[dofs] = f2bf(val - bf2f(h));
}

__device__ __forceinline__ void dev_pb_fold(const MegaP& P, float (*gw)[4][16], float (*c0s)[4], int tid) {
    if (tid < 12) {
        int i = tid >> 2, h = tid & 3;
        float c = 0.f;
        for (int cp = 0; cp < 16; ++cp) {
            float wp = P.w_pair[(i * 16 + cp) * 4 + h];
            gw[i][h][cp] = P.lnz_g[i * 16 + cp] * wp;
            c += P.lnz_b[i * 16 + cp] * wp;
        }
        c0s[i][h] = c;
    }
}

__device__ __forceinline__ void dev_pb(const MegaP& P, float (*gw)[4][16], float (*c0s)[4],
                                       int c, int yy, int tid) {
    int p = yy * 256 + tid;
    int ql_ = p >> 7, kl = p & 127;
    int kstart = max(0, c * 32 - 48), kend = min(2048, c * 32 + 80);
    int k = kstart + kl;
    if (k >= kend) {
#pragma unroll
        for (int i = 0; i < 3; ++i)
#pragma unroll
            for (int h = 0; h < 4; ++h)
                P.pb[((((size_t)i * 64 + c) * 4 + h) * 32 + ql_) * 128 + kl] = 0.f;
        return;
    }
    int q = c * 32 + ql_;
    const float* row = P.plm + ((size_t)q * 2048 + (size_t)k) * 16;
    float x[16];
#pragma unroll
    for (int j = 0; j < 4; ++j) {
        float4 v = *(const float4*)(row + j * 4);
        x[j * 4 + 0] = v.x; x[j * 4 + 1] = v.y; x[j * 4 + 2] = v.z; x[j * 4 + 3] = v.w;
    }
    float s = 0.f, sq = 0.f;
#pragma unroll
    for (int cp = 0; cp < 16; ++cp) { s += x[cp]; sq += x[cp] * x[cp]; }
    float mean = s * (1.f / 16.f);
    float var = sq * (1.f / 16.f) - mean * mean;
    float r = 1.f / sqrtf(var + 1e-5f);
    float xn[16];
#pragma unroll
    for (int cp = 0; cp < 16; ++cp) xn[cp] = (x[cp] - mean) * r;
#pragma unroll
    for (int i = 0; i < 3; ++i)
#pragma unroll
        for (int h = 0; h < 4; ++h) {
            float d = c0s[i][h];
#pragma unroll
            for (int cp = 0; cp < 16; ++cp) d = fmaf(xn[cp], gw[i][h][cp], d);
            P.pb[((((size_t)i * 64 + c) * 4 + h) * 32 + ql_) * 128 + kl] = d;
        }
}

// p1f task: LN/copy of cl rows -> LDS -> GEMM chunk -> sg. Contains __syncthreads.
__device__ __forceinline__ void dev_p1f(const MegaP& P, int x_, int chunk, int z, int tid,
                                        u16* Ah, u16* Al) {
    const int r0 = x_ * 32;
    {
        const int row = tid >> 3, cb = (tid & 7) * 16;
        const float* ar = P.cl + (size_t)(r0 + row) * CD + cb;
        float x[16];
#pragma unroll
        for (int j = 0; j < 4; ++j) {
            float4 v = *(const float4*)(ar + j * 4);
            x[4 * j] = v.x; x[4 * j + 1] = v.y; x[4 * j + 2] = v.z; x[4 * j + 3] = v.w;
        }
        float s = 0.f, sq = 0.f;
#pragma unroll
        for (int j = 0; j < 16; ++j) { s += x[j]; sq += x[j] * x[j]; }
#pragma unroll
        for (int m = 1; m < 8; m <<= 1) { s += __shfl_xor(s, m); sq += __shfl_xor(sq, m); }
        float mean = s * (1.f / 128.f), var = sq * (1.f / 128.f) - mean * mean;
        float rr = 1.f / sqrtf(var + 1e-5f);
#pragma unroll
        for (int gp = 0; gp < 2; ++gp) {
            u16 hv8[8], lv8[8];
#pragma unroll
            for (int j = 0; j < 8; ++j) {
                float xv = x[gp * 8 + j];
                float val = (chunk < 4) ? (xv - mean) * rr : xv;
                u16 hh = f2bf(val);
                hv8[j] = hh; lv8[j] = f2bf(val - bf2f(hh));
            }
            int g = ((cb >> 3) + gp) ^ (row & 7);
            *(s8v*)(Ah + row * 128 + g * 8) = *(s8v*)hv8;
            *(s8v*)(Al + row * 128 + g * 8) = *(s8v*)lv8;
        }
    }
    __syncthreads();
    const int l = tid & 63, wv_ = tid >> 6;
    const int lr = l & 15, lq = l >> 4, kg = lq * 8;
    const int c0 = wv_ * 32;
    const u16* Bh = P.BP1h + (size_t)z * 98304 + (size_t)chunk * 16384;
    const u16* Bl = P.BP1l + (size_t)z * 98304 + (size_t)chunk * 16384;
    f4v acc[2][2] = {};
#pragma unroll
    for (int ks = 0; ks < 4; ++ks) {
        int g = (4 * ks + lq) ^ (lr & 7);
        s8v a0h = *(const s8v*)(Ah + lr * 128 + g * 8);
        s8v a1h = *(const s8v*)(Ah + (16 + lr) * 128 + g * 8);
        s8v a0l = *(const s8v*)(Al + lr * 128 + g * 8);
        s8v a1l = *(const s8v*)(Al + (16 + lr) * 128 + g * 8);
        s8v b0h = *(const s8v*)(Bh + (size_t)(c0 + lr) * 128 + ks * 32 + kg);
        s8v b1h = *(const s8v*)(Bh + (size_t)(c0 + 16 + lr) * 128 + ks * 32 + kg);
        s8v b0l = *(const s8v*)(Bl + (size_t)(c0 + lr) * 128 + ks * 32 + kg);
        s8v b1l = *(const s8v*)(Bl + (size_t)(c0 + 16 + lr) * 128 + ks * 32 + kg);
        acc[0][0] = MFMA(a0h, b0h, acc[0][0], 0, 0, 0); acc[0][1] = MFMA(a0h, b1h, acc[0][1], 0, 0, 0);
        acc[1][0] = MFMA(a1h, b0h, acc[1][0], 0, 0, 0); acc[1][1] = MFMA(a1h, b1h, acc[1][1], 0, 0, 0);
        acc[0][0] = MFMA(a0h, b0l, acc[0][0], 0, 0, 0); acc[0][1] = MFMA(a0h, b1l, acc[0][1], 0, 0, 0);
        acc[1][0] = MFMA(a1h, b0l, acc[1][0], 0, 0, 0); acc[1][1] = MFMA(a1h, b1l, acc[1][1], 0, 0, 0);
        acc[0][0] = MFMA(a0l, b0h, acc[0][0], 0, 0, 0); acc[0][1] = MFMA(a0l, b1h, acc[0][1], 0, 0, 0);
        acc[1][0] = MFMA(a1l, b0h, acc[1][0], 0, 0, 0); acc[1][1] = MFMA(a1l, b1h, acc[1][1], 0, 0, 0);
    }
    const bool dosig = (chunk != 1) && (chunk != 3);
    const float* bp = P.Pbias + (z * 6 + chunk) * 128;
    float* dst = P.sg + ((size_t)z * 6 + chunk) * NC;
#pragma unroll
    for (int mi = 0; mi < 2; ++mi)
#pragma unroll
        for (int i = 0; i < 4; ++i) {
            int row = r0 + mi * 16 + lq * 4 + i;
#pragma unroll
            for (int ni = 0; ni < 2; ++ni) {
                int col = c0 + ni * 16 + lr;
                float xx = acc[mi][ni][i];
                if (dosig) xx = sigm(xx + bp[col]);
                dst[(size_t)row * CD + col] = xx;
            }
        }
    __syncthreads();
}

// k1 task: fused adaLN + QKVG/t1t2 GEMM for (r0, y). Contains __syncthreads.
__device__ __forceinline__ void dev_k1(const MegaP& P, int ib, int r0, int y, int tid,
                                       u16* Ah, u16* Al) {
    const float* a_cur = (ib == 0) ? P.ql : P.a_buf;
    const float* sgi = P.sg + (size_t)ib * 6 * NC;
    const u16* B1h = P.BG1h + (size_t)ib * 131072;
    const u16* B1l = P.BG1l + (size_t)ib * 131072;
    const float* bqz = P.bq + (size_t)ib * 128;
    {
        const int row = tid >> 3, cb = (tid & 7) * 16;
        const float* ar = a_cur + (size_t)(r0 + row) * CD + cb;
        float x[16];
#pragma unroll
        for (int j = 0; j < 4; ++j) {
            float4 v = *(const float4*)(ar + j * 4);
            x[4 * j] = v.x; x[4 * j + 1] = v.y; x[4 * j + 2] = v.z; x[4 * j + 3] = v.w;
        }
        float s = 0.f, sq = 0.f;
#pragma unroll
        for (int j = 0; j < 16; ++j) { s += x[j]; sq += x[j] * x[j]; }
#pragma unroll
        for (int m = 1; m < 8; m <<= 1) { s += __shfl_xor(s, m); sq += __shfl_xor(sq, m); }
        float mean = s * (1.f / 128.f), var = sq * (1.f / 128.f) - mean * mean;
        float rr = 1.f / sqrtf(var + 1e-5f);
        const float* sig = sgi + ((y < 2) ? 0 : 2 * NC) + (size_t)(r0 + row) * CD + cb;
        const float* skp = sgi + ((y < 2) ? NC : 3 * NC) + (size_t)(r0 + row) * CD + cb;
#pragma unroll
        for (int gp = 0; gp < 2; ++gp) {
            u16 hv8[8], lv8[8];
#pragma unroll
            for (int j = 0; j < 8; ++j) {
                int jj = gp * 8 + j;
                float ln = (x[jj] - mean) * rr;
                float val = fmaf(sig[jj], ln, skp[jj]);
                u16 hh = f2bf(val);
                hv8[j] = hh; lv8[j] = f2bf(val - bf2f(hh));
            }
            int g = ((cb >> 3) + gp) ^ (row & 7);
            *(s8v*)(Ah + row * 128 + g * 8) = *(s8v*)hv8;
            *(s8v*)(Al + row * 128 + g * 8) = *(s8v*)lv8;
        }
    }
    __syncthreads();
    const int l = tid & 63, wv_ = tid >> 6;
    const int lr = l & 15, lq = l >> 4, kg = lq * 8;
    const int chunk = 2 * y + (wv_ >> 1);
    const int cbase = (wv_ & 1) * 64;
    f4v acc[2][2][2] = {};
#pragma unroll
    for (int ks = 0; ks < 4; ++ks) {
        int g = (4 * ks + lq) ^ (lr & 7);
        s8v a0h = *(const s8v*)(Ah + lr * 128 + g * 8);
        s8v a1h = *(const s8v*)(Ah + (16 + lr) * 128 + g * 8);
        s8v a0l = *(const s8v*)(Al + lr * 128 + g * 8);
        s8v a1l = *(const s8v*)(Al + (16 + lr) * 128 + g * 8);
#pragma unroll
        for (int t2 = 0; t2 < 2; ++t2) {
            int crow = chunk * 128 + cbase + t2 * 32;
            s8v b0h = *(const s8v*)(B1h + (size_t)(crow + lr) * 128 + ks * 32 + kg);
            s8v b1h = *(const s8v*)(B1h + (size_t)(crow + 16 + lr) * 128 + ks * 32 + kg);
            s8v b0l = *(const s8v*)(B1l + (size_t)(crow + lr) * 128 + ks * 32 + kg);
            s8v b1l = *(const s8v*)(B1l + (size_t)(crow + 16 + lr) * 128 + ks * 32 + kg);
            acc[t2][0][0] = MFMA(a0h, b0h, acc[t2][0][0], 0, 0, 0);
            acc[t2][0][1] = MFMA(a0h, b1h, acc[t2][0][1], 0, 0, 0);
            acc[t2][1][0] = MFMA(a1h, b0h, acc[t2][1][0], 0, 0, 0);
            acc[t2][1][1] = MFMA(a1h, b1h, acc[t2][1][1], 0, 0, 0);
            acc[t2][0][0] = MFMA(a0h, b0l, acc[t2][0][0], 0, 0, 0);
            acc[t2][0][1] = MFMA(a0h, b1l, acc[t2][0][1], 0, 0, 0);
            acc[t2][1][0] = MFMA(a1h, b0l, acc[t2][1][0], 0, 0, 0);
            acc[t2][1][1] = MFMA(a1h, b1l, acc[t2][1][1], 0, 0, 0);
            acc[t2][0][0] = MFMA(a0l, b0h, acc[t2][0][0], 0, 0, 0);
            acc[t2][0][1] = MFMA(a0l, b1h, acc[t2][0][1], 0, 0, 0);
            acc[t2][1][0] = MFMA(a1l, b0h, acc[t2][1][0], 0, 0, 0);
            acc[t2][1][1] = MFMA(a1l, b1h, acc[t2][1][1], 0, 0, 0);
        }
    }
#pragma unroll
    for (int t2 = 0; t2 < 2; ++t2)
#pragma unroll
        for (int mi = 0; mi < 2; ++mi)
#pragma unroll
            for (int i = 0; i < 4; ++i) {
                int row = r0 + mi * 16 + lq * 4 + i;
#pragma unroll
                for (int ni = 0; ni < 2; ++ni) {
                    int gcol = chunk * 128 + cbase + t2 * 32 + ni * 16 + lr;
                    float x = acc[t2][mi][ni][i];
                    if (chunk == 0) x += bqz[gcol];
                    if (gcol < 512) {
                        u16 hh = f2bf(x), ll = f2bf(x - bf2f(hh));
                        P.qgh[(size_t)row * 512 + gcol] = hh;
                        P.qgl[(size_t)row * 512 + gcol] = ll;
                        if (chunk == 2) {
                            int cv = gcol - 256;
                            P.vTh[(size_t)cv * 2048 + row] = hh;
                            P.vTl[(size_t)cv * 2048 + row] = ll;
                        }
                    } else {
                        P.tbuf[(size_t)row * 512 + (gcol - 512)] = x;
                    }
                }
            }
    __syncthreads();
}

// attn task for (c,h); P stored hi+lo in LDS (2-term PV). Contains __syncthreads.
__device__ __forceinline__ void dev_attn(const MegaP& P, int ib, int c, int h,
                                         int tid, bool act, int mi, u16* Pls, u16* Pll) {
    const int l = tid & 63;
    const int kstart = max(0, c * 32 - 48);
    const int kend = min(2048, c * 32 + 80);
    const int nk = kend - kstart;
    const int lr = l & 15, lq = l >> 4, kg = lq * 8;
    const float* pbp = P.pb + (size_t)ib * 4 * NC + (size_t)((c * 4 + h) * 32) * 128;
    f4v oac[2] = {};
    float inv_s[4];
    if (act) {
        s8v qfh, qfl;
        {
            size_t qb = (size_t)(c * 32 + mi * 16 + lr) * 512 + h * 32 + kg;
            qfh = *(const s8v*)(P.qgh + qb);
            qfl = *(const s8v*)(P.qgl + qb);
        }
        f4v lac[8] = {};
#pragma unroll
        for (int kt = 0; kt < 8; ++kt) {
            int krow = min(kstart + kt * 16 + lr, 2047);
            size_t kb = (size_t)krow * 512 + 128 + h * 32 + kg;
            s8v bh = *(const s8v*)(P.qgh + kb);
            s8v bl = *(const s8v*)(P.qgl + kb);
            lac[kt] = MFMA(qfh, bh, lac[kt], 0, 0, 0);
            lac[kt] = MFMA(qfh, bl, lac[kt], 0, 0, 0);
            lac[kt] = MFMA(qfl, bh, lac[kt], 0, 0, 0);
        }
        float mb8[8];
#pragma unroll
        for (int kt = 0; kt < 8; ++kt) {
            int kl = kt * 16 + lr;
            mb8[kt] = (kl < nk) ? (P.atom_mask[kstart + kl] - 1.f) * 1.0e9f : 0.f;
        }
        const float scale = 0.17677669529663687f;
#pragma unroll
        for (int i = 0; i < 4; ++i) {
            const int rl = mi * 16 + lq * 4 + i;
            float lg[8];
#pragma unroll
            for (int kt = 0; kt < 8; ++kt) {
                int kl = kt * 16 + lr;
                float v = -1e30f;
                if (kl < nk) v = fmaf(lac[kt][i], scale, pbp[(size_t)rl * 128 + kl] + mb8[kt]);
                lg[kt] = v;
            }
            float m = lg[0];
#pragma unroll
            for (int kt = 1; kt < 8; ++kt) m = fmaxf(m, lg[kt]);
#pragma unroll
            for (int msk = 1; msk < 16; msk <<= 1) m = fmaxf(m, __shfl_xor(m, msk));
            float ssum = 0.f;
#pragma unroll
            for (int kt = 0; kt < 8; ++kt) {
                float p = __expf(lg[kt] - m);
                ssum += p;
                u16 p16 = f2bf(p);
                int kl = kt * 16 + lr;
                int g = (kl >> 3) ^ (rl & 7);
                Pls[rl * 128 + g * 8 + (kl & 7)] = p16;
                Pll[rl * 128 + g * 8 + (kl & 7)] = f2bf(p - bf2f(p16));
            }
#pragma unroll
            for (int msk = 1; msk < 16; msk <<= 1) ssum += __shfl_xor(ssum, msk);
            inv_s[i] = 1.f / ssum;
        }
    }
    __syncthreads();   // P tiles fully in LDS before vector re-read
    if (act) {
#pragma unroll
        for (int ks = 0; ks < 4; ++ks) {
            int prow = mi * 16 + lr;
            int g = (4 * ks + lq) ^ (prow & 7);
            s8v pA = *(const s8v*)(Pls + prow * 128 + g * 8);
            s8v pAl = *(const s8v*)(Pll + prow * 128 + g * 8);
            int kcol = kstart + ks * 32 + kg;
            if (kcol > 2040) kcol = 0;   // clamped slots have P == 0 exactly
#pragma unroll
            for (int ct = 0; ct < 2; ++ct) {
                size_t vb = (size_t)(h * 32 + ct * 16 + lr) * 2048 + kcol;
                s8v vh = *(const s8v*)(P.vTh + vb);
                s8v vl = *(const s8v*)(P.vTl + vb);
                oac[ct] = MFMA(pA, vh, oac[ct], 0, 0, 0);
                oac[ct] = MFMA(pA, vl, oac[ct], 0, 0, 0);
                oac[ct] = MFMA(pAl, vh, oac[ct], 0, 0, 0);
            }
        }
#pragma unroll
        for (int ct = 0; ct < 2; ++ct)
#pragma unroll
            for (int i = 0; i < 4; ++i) {
                int rl = mi * 16 + lq * 4 + i;
                int row = c * 32 + rl;
                int d = ct * 16 + lr;
                float o = oac[ct][i] * inv_s[i];
                size_t gidx = (size_t)row * 512 + 384 + h * 32 + d;
                float g = bf2f(P.qgh[gidx]) + bf2f(P.qgl[gidx]);
                float v = o * sigm(g);
                u16 hh = f2bf(v);
                size_t oi = (size_t)row * 128 + h * 32 + d;
                P.ogh[oi] = hh;
                P.ogl[oi] = f2bf(v - bf2f(hh));
            }
    }
}

// k3 task for r0. Contains __syncthreads.
__device__ __forceinline__ void dev_k3(const MegaP& P, int ib, int r0, int tid,
                                       u16* Sh, u16* Sl) {
    const u16* B2h = P.BG2h + (size_t)ib * 49152;
    const u16* B2l = P.BG2l + (size_t)ib * 49152;
    const float* sg4 = P.sg + (size_t)ib * 6 * NC + 4 * NC;
    const float* sg5 = P.sg + (size_t)ib * 6 * NC + 5 * NC;
    float* dst = (ib == 2) ? P.out : P.a_buf;
    {
        const int row = tid >> 3, cb = (tid & 7) * 32;
#pragma unroll
        for (int u = 0; u < 4; ++u) {
            int colb = cb + u * 8;
            const float* t1 = P.tbuf + (size_t)(r0 + row) * 512 + colb;
            const float* t2 = t1 + 256;
            u16 hv8[8], lv8[8];
#pragma unroll
            for (int j2 = 0; j2 < 2; ++j2) {
                float4 x1 = *(const float4*)(t1 + j2 * 4);
                float4 x2 = *(const float4*)(t2 + j2 * 4);
                float sv[4];
                sv[0] = x1.x * sigm(x1.x) * x2.x;
                sv[1] = x1.y * sigm(x1.y) * x2.y;
                sv[2] = x1.z * sigm(x1.z) * x2.z;
                sv[3] = x1.w * sigm(x1.w) * x2.w;
#pragma unroll
                for (int j = 0; j < 4; ++j) {
                    u16 hh = f2bf(sv[j]);
                    hv8[j2 * 4 + j] = hh;
                    lv8[j2 * 4 + j] = f2bf(sv[j] - bf2f(hh));
                }
            }
            int g = (colb >> 3) ^ (row & 7);
            *(s8v*)(Sh + row * 256 + g * 8) = *(s8v*)hv8;
            *(s8v*)(Sl + row * 256 + g * 8) = *(s8v*)lv8;
        }
    }
    __syncthreads();
    const int l = tid & 63, wv_ = tid >> 6;
    const int lr = l & 15, lq = l >> 4, kg = lq * 8;
    const int c0 = wv_ * 32;
    f4v ac1[2][2] = {}, ac2[2][2] = {};
#pragma unroll
    for (int ks = 0; ks < 4; ++ks) {
        s8v a0h = *(const s8v*)(P.ogh + (size_t)(r0 + lr) * 128 + ks * 32 + kg);
        s8v a1h = *(const s8v*)(P.ogh + (size_t)(r0 + 16 + lr) * 128 + ks * 32 + kg);
        s8v a0l = *(const s8v*)(P.ogl + (size_t)(r0 + lr) * 128 + ks * 32 + kg);
        s8v a1l = *(const s8v*)(P.ogl + (size_t)(r0 + 16 + lr) * 128 + ks * 32 + kg);
        s8v b0h = *(const s8v*)(B2h + (size_t)(c0 + lr) * 384 + ks * 32 + kg);
        s8v b1h = *(const s8v*)(B2h + (size_t)(c0 + 16 + lr) * 384 + ks * 32 + kg);
        s8v b0l = *(const s8v*)(B2l + (size_t)(c0 + lr) * 384 + ks * 32 + kg);
        s8v b1l = *(const s8v*)(B2l + (size_t)(c0 + 16 + lr) * 384 + ks * 32 + kg);
        ac1[0][0] = MFMA(a0h, b0h, ac1[0][0], 0, 0, 0); ac1[0][1] = MFMA(a0h, b1h, ac1[0][1], 0, 0, 0);
        ac1[1][0] = MFMA(a1h, b0h, ac1[1][0], 0, 0, 0); ac1[1][1] = MFMA(a1h, b1h, ac1[1][1], 0, 0, 0);
        ac1[0][0] = MFMA(a0h, b0l, ac1[0][0], 0, 0, 0); ac1[0][1] = MFMA(a0h, b1l, ac1[0][1], 0, 0, 0);
        ac1[1][0] = MFMA(a1h, b0l, ac1[1][0], 0, 0, 0); ac1[1][1] = MFMA(a1h, b1l, ac1[1][1], 0, 0, 0);
        ac1[0][0] = MFMA(a0l, b0h, ac1[0][0], 0, 0, 0); ac1[0][1] = MFMA(a0l, b1h, ac1[0][1], 0, 0, 0);
        ac1[1][0] = MFMA(a1l, b0h, ac1[1][0], 0, 0, 0); ac1[1][1] = MFMA(a1l, b1h, ac1[1][1], 0, 0, 0);
    }
#pragma unroll
    for (int ks = 0; ks < 8; ++ks) {
        int g = (4 * ks + lq) ^ (lr & 7);
        s8v a0h = *(const s8v*)(Sh + lr * 256 + g * 8);
        s8v a1h = *(const s8v*)(Sh + (16 + lr) * 256 + g * 8);
        s8v a0l = *(const s8v*)(Sl + lr * 256 + g * 8);
        s8v a1l = *(const s8v*)(Sl + (16 + lr) * 256 + g * 8);
        s8v b0h = *(const s8v*)(B2h + (size_t)(c0 + lr) * 384 + 128 + ks * 32 + kg);
        s8v b1h = *(const s8v*)(B2h + (size_t)(c0 + 16 + lr) * 384 + 128 + ks * 32 + kg);
        s8v b0l = *(const s8v*)(B2l + (size_t)(c0 + lr) * 384 + 128 + ks * 32 + kg);
        s8v b1l = *(const s8v*)(B2l + (size_t)(c0 + 16 + lr) * 384 + 128 + ks * 32 + kg);
        ac2[0][0] = MFMA(a0h, b0h, ac2[0][0], 0, 0, 0); ac2[0][1] = MFMA(a0h, b1h, ac2[0][1], 0, 0, 0);
        ac2[1][0] = MFMA(a1h, b0h, ac2[1][0], 0, 0, 0); ac2[1][1] = MFMA(a1h, b1h, ac2[1][1], 0, 0, 0);
        ac2[0][0] = MFMA(a0h, b0l, ac2[0][0], 0, 0, 0); ac2[0][1] = MFMA(a0h, b1l, ac2[0][1], 0, 0, 0);
        ac2[1][0] = MFMA(a1h, b0l, ac2[1][0], 0, 0, 0); ac2[1][1] = MFMA(a1h, b1l, ac2[1][1], 0, 0, 0);
        ac2[0][0] = MFMA(a0l, b0h, ac2[0][0], 0, 0, 0); ac2[0][1] = MFMA(a0l, b1h, ac2[0][1], 0, 0, 0);
        ac2[1][0] = MFMA(a1l, b0h, ac2[1][0], 0, 0, 0); ac2[1][1] = MFMA(a1l, b1h, ac2[1][1], 0, 0, 0);
    }
#pragma unroll
    for (int mi = 0; mi < 2; ++mi)
#pragma unroll
        for (int i = 0; i < 4; ++i) {
            int row = r0 + mi * 16 + lq * 4 + i;
#pragma unroll
            for (int ni = 0; ni < 2; ++ni) {
                int col = c0 + ni * 16 + lr;
                size_t idx = (size_t)row * CD + col;
                dst[idx] = sg4[idx] * ac1[mi][ni][i] + sg5[idx] * ac2[mi][ni][i];
            }
        }
    __syncthreads();
}

// ======================= kernels =======================

__global__ __launch_bounds__(256) void prep_w_k(MegaP P) {
    dev_prep(P, blockIdx.x * 256 + threadIdx.x);
}

// blocks [0,1152): p1f task; blocks [1152, 2176): pb task
__global__ __launch_bounds__(256) void combo_pp(MegaP P) {
    int bx = blockIdx.x;
    if (bx < 1152) {
        __shared__ u16 Ah[32 * 128], Al[32 * 128];
        int x_ = bx & 63, rem = bx >> 6;
        dev_p1f(P, x_, rem % 6, rem / 6, threadIdx.x, Ah, Al);
    } else {
        __shared__ float gw[3][4][16];
        __shared__ float c0s[3][4];
        dev_pb_fold(P, gw, c0s, threadIdx.x);
        __syncthreads();
        int pt = bx - 1152;
        dev_pb(P, gw, c0s, pt & 63, pt >> 6, threadIdx.x);
    }
}

__global__ __launch_bounds__(256) void k1_k(MegaP P, int ib) {
    __shared__ u16 Ah[32 * 128], Al[32 * 128];
    dev_k1(P, ib, blockIdx.x * 32, blockIdx.y, threadIdx.x, Ah, Al);
}

__global__ __launch_bounds__(128) void attn_k(MegaP P, int ib) {
    __shared__ u16 Pls[32 * 128], Pll[32 * 128];
    dev_attn(P, ib, blockIdx.x, blockIdx.y, threadIdx.x, true, threadIdx.x >> 6, Pls, Pll);
}

__global__ __launch_bounds__(256) void k3_k(MegaP P, int ib) {
    __shared__ u16 Sh[32 * 256], Sl[32 * 256];
    dev_k3(P, ib, blockIdx.x * 32, threadIdx.x, Sh, Sl);
}

extern "C" void kernel_launch(void* const* d_in, const int* in_sizes, int n_in,
                              void* d_out, int out_size, void* d_ws, size_t ws_size,
                              hipStream_t stream) {
    float* ws = (float*)d_ws;

    MegaP P;
    P.ql = (const float*)d_in[0];
    P.cl = (const float*)d_in[1];
    P.plm = (const float*)d_in[2];
    P.atom_mask = (const float*)d_in[3];
    P.attn_gamma = (const float*)d_in[4];
    P.attn_wsig = (const float*)d_in[5];
    P.attn_bsig = (const float*)d_in[6];
    P.attn_wskip = (const float*)d_in[7];
    P.wq = (const float*)d_in[8];
    P.bq = (const float*)d_in[9];
    P.wk = (const float*)d_in[10];
    P.wv = (const float*)d_in[11];
    P.lnz_g = (const float*)d_in[12];
    P.lnz_b = (const float*)d_in[13];
    P.w_pair = (const float*)d_in[14];
    P.w_gate = (const float*)d_in[15];
    P.w_out = (const float*)d_in[16];
    P.w_ao = (const float*)d_in[17];
    P.b_ao = (const float*)d_in[18];
    P.tr_gamma = (const float*)d_in[19];
    P.tr_wsig = (const float*)d_in[20];
    P.tr_bsig = (const float*)d_in[21];
    P.tr_wskip = (const float*)d_in[22];
    P.w_t1 = (const float*)d_in[23];
    P.w_t2 = (const float*)d_in[24];
    P.w_t3 = (const float*)d_in[25];
    P.w_to = (const float*)d_in[26];
    P.b_to = (const float*)d_in[27];
    P.out = (float*)d_out;

    P.sg = ws;                        // 18 NC
    P.tbuf = ws + 18 * NC;            // 4 NC
    P.pb = ws + 22 * NC;              // 12 NC
    P.a_buf = ws + 34 * NC;           // 1 NC
    P.Pbias = ws + 35 * NC;           // 2304 floats
    u16* us = (u16*)(ws + 36 * NC);
    P.qgh = us;
    P.qgl = P.qgh + 4 * NC;
    P.ogh = P.qgl + 4 * NC;
    P.ogl = P.ogh + NC;
    P.vTh = P.ogl + NC;
    P.vTl = P.vTh + NC + 128;
    P.BP1h = P.vTl + NC + 128;
    P.BP1l = P.BP1h + 294912;
    P.BG1h = P.BP1l + 294912;
    P.BG1l = P.BG1h + 393216;
    P.BG2h = P.BG1l + 393216;
    P.BG2l = P.BG2h + 147456;

    // NOTE: no workspace memset. Every buffer read below is fully written earlier
    // in this same call (coverage audit r8): sg/pb/Pbias/weights <- prep_w+combo_pp;
    // tbuf/qg/vT <- k1; og <- attn; a_buf <- k3(ib) before k1(ib+1). The round-7
    // profile showed the 47 MB hipMemsetAsync cost ~155 us/replay (~82% of total).

    prep_w_k<<<3273, 256, 0, stream>>>(P);
    combo_pp<<<2176, 256, 0, stream>>>(P);
    for (int ib = 0; ib < 3; ++ib) {
        k1_k<<<dim3(64, 4), 256, 0, stream>>>(P, ib);
        attn_k<<<dim3(64, 4), 128, 0, stream>>>(P, ib);
        k3_k<<<64, 256, 0, stream>>>(P, ib);
    }
}